// Round 14
// baseline (706.614 us; speedup 1.0000x reference)
//
#include <hip/hip_runtime.h>
#include <hip/hip_fp16.h>

// Instant-NGP grid encoder, MI355X (gfx950).
// N=2,000,000 points [N,3] f32 in [0,1); 12 levels, F=2; out [N,24] f32.
// res: 16,23,32,46,64,92,128,184,256,368,512,736; hash iff r^3>2^19
// (levels 5..11, each exactly 2^19 entries -> & 0x7FFFF). Dense: no modulo.
//
// Round-14: MORTON COUNTING-SORT of points, then gather.
//   r10-r13 elimination: bottleneck = per-wave distinct-64B-line transaction
//   count of random gathers (~108M transactions; load flavor irrelevant).
//   Sorting points into 64^3 Morton buckets makes adjacent lanes spatially
//   adjacent -> TCP coalescer merges same-line lanes within each gather
//   instruction (levels 0..7 collapse; 9..11 unchanged). Sorted order also
//   keeps stage writes coalesced; assemble scatters 96B rows to out[orig].
//   Output values are atomic-order independent -> deterministic.

namespace {
constexpr int NLEV = 12;
constexpr int BLOCK = 256;
constexpr int DENSE_A_END = 146368;   // levels 0..3
constexpr int L4_SIZE = 262144;       // level 4 (64^3)
constexpr int NBUCK = 262144;         // 64^3 Morton buckets
constexpr unsigned P1 = 2654435761u;
constexpr unsigned P2 = 805459861u;
constexpr unsigned HMASK = (1u << 19) - 1u;

__device__ __constant__ constexpr int kRes[NLEV] = {
    16, 23, 32, 46, 64, 92, 128, 184, 256, 368, 512, 736};
__device__ __constant__ constexpr int kOff[NLEV] = {
    0, 4096, 16264, 49032, 146368, 408512,
    932800, 1457088, 1981376, 2505664, 3029952, 3554240};

typedef float    f32x2 __attribute__((ext_vector_type(2)));
typedef unsigned u32x2 __attribute__((ext_vector_type(2)));
typedef unsigned u32x4 __attribute__((ext_vector_type(4)));

__device__ __forceinline__ unsigned pkh2(float a, float b) {
    __half2 h = __floats2half2_rn(a, b);
    return *reinterpret_cast<unsigned*>(&h);
}
__device__ __forceinline__ float lo2f(unsigned u) {
    __half2 h = *reinterpret_cast<__half2*>(&u);
    return __low2float(h);
}
__device__ __forceinline__ float hi2f(unsigned u) {
    __half2 h = *reinterpret_cast<__half2*>(&u);
    return __high2float(h);
}
__device__ __forceinline__ unsigned spread3(unsigned v) {
    v = (v | v << 16) & 0x030000FFu;
    v = (v | v << 8)  & 0x0300F00Fu;
    v = (v | v << 4)  & 0x030C30C3u;
    v = (v | v << 2)  & 0x09249249u;
    return v;
}
__device__ __forceinline__ unsigned morton6(float x, float y, float z) {
    unsigned ix = min(63u, (unsigned)(x * 64.0f));
    unsigned iy = min(63u, (unsigned)(y * 64.0f));
    unsigned iz = min(63u, (unsigned)(z * 64.0f));
    return spread3(ix) | (spread3(iy) << 1) | (spread3(iz) << 2);
}
}  // namespace

// ---- fused pre-pass: packed (all), quad (levels 0-3), pair4 (level 4) ----
__global__ void __launch_bounds__(BLOCK)
pack_all_kernel(const float2* __restrict__ emb,
                unsigned* __restrict__ packed,
                u32x4* __restrict__ quad,
                u32x2* __restrict__ pair4, int total)
{
    int i = blockIdx.x * BLOCK + threadIdx.x;
    if (i >= total) return;
    float2 v = emb[i];
    packed[i] = pkh2(v.x, v.y);
    if (i < DENSE_A_END) {
        int R = (i < 4096) ? 16 : (i < 16264) ? 23 : (i < 49032) ? 32 : 46;
        float2 e1 = emb[i + 1];
        float2 e2 = emb[i + R];
        float2 e3 = emb[i + R + 1];
        u32x4 q;
        q.x = pkh2(v.x, v.y);   q.y = pkh2(e1.x, e1.y);
        q.z = pkh2(e2.x, e2.y); q.w = pkh2(e3.x, e3.y);
        quad[i] = q;
    }
    if (i < L4_SIZE) {
        int g = DENSE_A_END + i;
        float2 a = emb[g];
        float2 b = emb[g + 1];
        u32x2 o; o.x = pkh2(a.x, a.y); o.y = pkh2(b.x, b.y);
        pair4[i] = o;
    }
}

// ---- sort pass 1: bucket histogram ----
__global__ void __launch_bounds__(BLOCK)
hist_kernel(const float* __restrict__ inp, unsigned* __restrict__ hist, int N)
{
    int n = blockIdx.x * BLOCK + threadIdx.x;
    if (n >= N) return;
    const float x = inp[3 * n + 0];
    const float y = inp[3 * n + 1];
    const float z = inp[3 * n + 2];
    atomicAdd(&hist[morton6(x, y, z)], 1u);
}

// ---- sort pass 2: exclusive scan (single block, in-place hist -> offsets) ----
__global__ void __launch_bounds__(1024)
scan_kernel(unsigned* __restrict__ hist)
{
    __shared__ unsigned s[1024];
    const int t = threadIdx.x;
    const int base = t * (NBUCK / 1024);     // 256 buckets per thread
    unsigned sum = 0;
    for (int i = 0; i < NBUCK / 1024; ++i) sum += hist[base + i];
    s[t] = sum;
    __syncthreads();
    for (int off = 1; off < 1024; off <<= 1) {
        unsigned v = (t >= off) ? s[t - off] : 0u;
        __syncthreads();
        s[t] += v;
        __syncthreads();
    }
    unsigned run = s[t] - sum;               // exclusive prefix
    for (int i = 0; i < NBUCK / 1024; ++i) {
        unsigned h = hist[base + i];
        hist[base + i] = run;                // in-place: now start offsets
        run += h;
    }
}

// ---- sort pass 3: scatter points to sorted order ----
__global__ void __launch_bounds__(BLOCK)
scatter_kernel(const float* __restrict__ inp, unsigned* __restrict__ offs,
               float4* __restrict__ sorted, int N)
{
    int n = blockIdx.x * BLOCK + threadIdx.x;
    if (n >= N) return;
    const float x = inp[3 * n + 0];
    const float y = inp[3 * n + 1];
    const float z = inp[3 * n + 2];
    unsigned pos = atomicAdd(&offs[morton6(x, y, z)], 1u);
    float4 o;
    o.x = x; o.y = y; o.z = z; o.w = __uint_as_float((unsigned)n);
    sorted[pos] = o;
}

// ---- hash level encode (plain loads; aligned x-pair words) ----
__device__ __forceinline__ unsigned
encode_hash_rt(float x, float y, float z, const unsigned* __restrict__ pt,
               float scale)
{
    const float px = x * scale, py = y * scale, pz = z * scale;
    const float fx = floorf(px), fy = floorf(py), fz = floorf(pz);
    const float rx = px - fx, ry = py - fy, rz = pz - fz;
    const unsigned ix = (unsigned)fx, iy = (unsigned)fy, iz = (unsigned)fz;
    const unsigned yA = iy * P1, yB = yA + P1;
    const unsigned zA = iz * P2, zB = zA + P2;
    const unsigned h00 = (ix ^ yA ^ zA) & HMASK;
    const unsigned h10 = (ix ^ yB ^ zA) & HMASK;
    const unsigned h01 = (ix ^ yA ^ zB) & HMASK;
    const unsigned h11 = (ix ^ yB ^ zB) & HMASK;

    const u32x2* pt2 = reinterpret_cast<const u32x2*>(pt);
    const u32x2 q00 = pt2[h00 >> 1];
    const u32x2 q10 = pt2[h10 >> 1];
    const u32x2 q01 = pt2[h01 >> 1];
    const u32x2 q11 = pt2[h11 >> 1];

    unsigned e00 = (h00 & 1) ? q00.y : q00.x;
    unsigned e10 = (h10 & 1) ? q10.y : q10.x;
    unsigned e01 = (h01 & 1) ? q01.y : q01.x;
    unsigned e11 = (h11 & 1) ? q11.y : q11.x;
    unsigned f00 = (h00 & 1) ? q00.x : q00.y;
    unsigned f10 = (h10 & 1) ? q10.x : q10.y;
    unsigned f01 = (h01 & 1) ? q01.x : q01.y;
    unsigned f11 = (h11 & 1) ? q11.x : q11.y;

    if (ix & 1u) {  // odd ix: sibling word is ix-1; need real ix+1 entries
        const unsigned xo = ix + 1u;
        f00 = pt[(xo ^ yA ^ zA) & HMASK];
        f10 = pt[(xo ^ yB ^ zA) & HMASK];
        f01 = pt[(xo ^ yA ^ zB) & HMASK];
        f11 = pt[(xo ^ yB ^ zB) & HMASK];
    }

    const float wx0 = 1.0f - rx, wx1 = rx;
    const float wy0 = 1.0f - ry, wy1 = ry;
    const float wz0 = 1.0f - rz, wz1 = rz;
    const float w00 = wy0 * wz0, w10 = wy1 * wz0;
    const float w01 = wy0 * wz1, w11 = wy1 * wz1;
    float sx = 0.0f, sy = 0.0f;
    sx = fmaf(w00 * wx0, lo2f(e00), fmaf(w00 * wx1, lo2f(f00), sx));
    sy = fmaf(w00 * wx0, hi2f(e00), fmaf(w00 * wx1, hi2f(f00), sy));
    sx = fmaf(w10 * wx0, lo2f(e10), fmaf(w10 * wx1, lo2f(f10), sx));
    sy = fmaf(w10 * wx0, hi2f(e10), fmaf(w10 * wx1, hi2f(f10), sy));
    sx = fmaf(w01 * wx0, lo2f(e01), fmaf(w01 * wx1, lo2f(f01), sx));
    sy = fmaf(w01 * wx0, hi2f(e01), fmaf(w01 * wx1, hi2f(f01), sy));
    sx = fmaf(w11 * wx0, lo2f(e11), fmaf(w11 * wx1, lo2f(f11), sx));
    sy = fmaf(w11 * wx0, hi2f(e11), fmaf(w11 * wx1, hi2f(f11), sy));
    return pkh2(sx, sy);
}

// ---- MEGA: blocks [0,CB)=dense_a, [CB,2CB)=dense_b, [2CB,9CB)=hash5..11 ----
template <int SORTED>
__global__ void __launch_bounds__(BLOCK)
mega_kernel(const float* __restrict__ inp, const float4* __restrict__ pts,
            const u32x4* __restrict__ quad,
            const u32x2* __restrict__ pair4,
            const unsigned* __restrict__ packed,
            unsigned* __restrict__ stage, int N, int CB)
{
    const int b = blockIdx.x;
    const int t = b / CB;            // task id (block-uniform)
    const int chunk = b - t * CB;
    const int g = chunk * BLOCK + threadIdx.x;   // point-pair index
    const int p0 = 2 * g;
    if (p0 >= N) return;
    const bool two = (p0 + 1 < N);

    float X[2], Y[2], Z[2];
    if (SORTED) {
        const float4 s0 = pts[p0];
        const float4 s1 = two ? pts[p0 + 1] : s0;
        X[0] = s0.x; X[1] = s1.x;
        Y[0] = s0.y; Y[1] = s1.y;
        Z[0] = s0.z; Z[1] = s1.z;
    } else {
        const f32x2* ip2 = reinterpret_cast<const f32x2*>(inp);
        f32x2 v0 = ip2[3 * g + 0];
        f32x2 v1, v2;
        if (two) { v1 = ip2[3 * g + 1]; v2 = ip2[3 * g + 2]; }
        else { v1.x = inp[3 * p0 + 2]; v1.y = 0.f; v2.x = 0.f; v2.y = 0.f; }
        X[0] = v0.x; X[1] = v1.y;
        Y[0] = v0.y; Y[1] = v2.x;
        Z[0] = v1.x; Z[1] = v2.y;
    }

    if (t == 0) {
        // dense levels 0..3, quad gathers (16B entries)
#pragma unroll
        for (int l = 0; l < 4; ++l) {
            const unsigned R = (unsigned)kRes[l];
            const unsigned R2 = R * R;
            const float scale = (float)(kRes[l] - 1);
            const u32x4* qt = quad + kOff[l];
            u32x2 res;
#pragma unroll
            for (int k = 0; k < 2; ++k) {
                const float px = X[k] * scale, py = Y[k] * scale,
                            pz = Z[k] * scale;
                const float fx = floorf(px), fy = floorf(py), fz = floorf(pz);
                const float rx = px - fx, ry = py - fy, rz = pz - fz;
                const unsigned ix = (unsigned)fx, iy = (unsigned)fy,
                               iz = (unsigned)fz;
                const unsigned base = ix + iy * R + iz * R2;
                const u32x4 q0 = qt[base];
                const u32x4 q1 = qt[base + R2];
                const float wx0 = 1.0f - rx, wx1 = rx;
                const float wy0 = 1.0f - ry, wy1 = ry;
                const float wz0 = 1.0f - rz, wz1 = rz;
                const float ex00 = wx0 * lo2f(q0.x) + wx1 * lo2f(q0.y);
                const float ey00 = wx0 * hi2f(q0.x) + wx1 * hi2f(q0.y);
                const float ex10 = wx0 * lo2f(q0.z) + wx1 * lo2f(q0.w);
                const float ey10 = wx0 * hi2f(q0.z) + wx1 * hi2f(q0.w);
                const float ex01 = wx0 * lo2f(q1.x) + wx1 * lo2f(q1.y);
                const float ey01 = wx0 * hi2f(q1.x) + wx1 * hi2f(q1.y);
                const float ex11 = wx0 * lo2f(q1.z) + wx1 * lo2f(q1.w);
                const float ey11 = wx0 * hi2f(q1.z) + wx1 * hi2f(q1.w);
                const float sx = wz0 * (wy0 * ex00 + wy1 * ex10) +
                                 wz1 * (wy0 * ex01 + wy1 * ex11);
                const float sy = wz0 * (wy0 * ey00 + wy1 * ey10) +
                                 wz1 * (wy0 * ey01 + wy1 * ey11);
                res[k] = pkh2(sx, sy);
            }
            if (two) {
                __builtin_nontemporal_store(
                    res,
                    reinterpret_cast<u32x2*>(&stage[(long long)l * N + p0]));
            } else {
                __builtin_nontemporal_store(res.x,
                                            &stage[(long long)l * N + p0]);
            }
        }
    } else if (t == 1) {
        // dense level 4 (64^3), pair gathers (8B entries)
        constexpr unsigned R = 64, R2 = 4096;
        constexpr float scale = 63.0f;
        u32x2 res;
#pragma unroll
        for (int k = 0; k < 2; ++k) {
            const float px = X[k] * scale, py = Y[k] * scale, pz = Z[k] * scale;
            const float fx = floorf(px), fy = floorf(py), fz = floorf(pz);
            const float rx = px - fx, ry = py - fy, rz = pz - fz;
            const unsigned ix = (unsigned)fx, iy = (unsigned)fy,
                           iz = (unsigned)fz;
            const unsigned base = ix + iy * R + iz * R2;
            const u32x2 q00 = pair4[base];
            const u32x2 q10 = pair4[base + R];
            const u32x2 q01 = pair4[base + R2];
            const u32x2 q11 = pair4[base + R2 + R];
            const float wx0 = 1.0f - rx, wx1 = rx;
            const float wy0 = 1.0f - ry, wy1 = ry;
            const float wz0 = 1.0f - rz, wz1 = rz;
            const float w00 = wy0 * wz0, w10 = wy1 * wz0;
            const float w01 = wy0 * wz1, w11 = wy1 * wz1;
            float sx = 0.0f, sy = 0.0f;
            sx = fmaf(w00 * wx0, lo2f(q00.x), fmaf(w00 * wx1, lo2f(q00.y), sx));
            sy = fmaf(w00 * wx0, hi2f(q00.x), fmaf(w00 * wx1, hi2f(q00.y), sy));
            sx = fmaf(w10 * wx0, lo2f(q10.x), fmaf(w10 * wx1, lo2f(q10.y), sx));
            sy = fmaf(w10 * wx0, hi2f(q10.x), fmaf(w10 * wx1, hi2f(q10.y), sy));
            sx = fmaf(w01 * wx0, lo2f(q01.x), fmaf(w01 * wx1, lo2f(q01.y), sx));
            sy = fmaf(w01 * wx0, hi2f(q01.x), fmaf(w01 * wx1, hi2f(q01.y), sy));
            sx = fmaf(w11 * wx0, lo2f(q11.x), fmaf(w11 * wx1, lo2f(q11.y), sx));
            sy = fmaf(w11 * wx0, hi2f(q11.x), fmaf(w11 * wx1, hi2f(q11.y), sy));
            res[k] = pkh2(sx, sy);
        }
        unsigned* s4 = stage + 4LL * N;
        if (two) {
            __builtin_nontemporal_store(res, reinterpret_cast<u32x2*>(&s4[p0]));
        } else {
            __builtin_nontemporal_store(res.x, &s4[p0]);
        }
    } else {
        // hash level L = t + 3 (t=2..8 -> L=5..11)
        const int L = t + 3;
        const float scale = (float)(kRes[L] - 1);
        const unsigned* pt = packed + kOff[L];
        u32x2 res;
        res.x = encode_hash_rt(X[0], Y[0], Z[0], pt, scale);
        res.y = two ? encode_hash_rt(X[1], Y[1], Z[1], pt, scale) : 0u;
        unsigned* sl = stage + (long long)L * N;
        if (two) {
            __builtin_nontemporal_store(res, reinterpret_cast<u32x2*>(&sl[p0]));
        } else {
            __builtin_nontemporal_store(res.x, &sl[p0]);
        }
    }
}

// ---- final (sorted path): stage[12][N] sorted -> out[orig][24] scatter ----
__global__ void __launch_bounds__(BLOCK)
assemble_scatter_kernel(const unsigned* __restrict__ lvl,
                        const float4* __restrict__ pts,
                        float* __restrict__ out, int N)
{
    const int n = blockIdx.x * BLOCK + threadIdx.x;
    if (n >= N) return;
    float vals[24];
#pragma unroll
    for (int l = 0; l < NLEV; ++l) {
        unsigned u = lvl[(long long)l * N + n];   // coalesced per level
        vals[2 * l + 0] = lo2f(u);
        vals[2 * l + 1] = hi2f(u);
    }
    const unsigned o = __float_as_uint(pts[n].w);
    float4* op = reinterpret_cast<float4*>(out + (size_t)o * 24);
#pragma unroll
    for (int k = 0; k < 6; ++k) {
        float4 v;
        v.x = vals[4 * k + 0]; v.y = vals[4 * k + 1];
        v.z = vals[4 * k + 2]; v.w = vals[4 * k + 3];
        op[k] = v;   // 96B row spans 2 cache lines; values order-independent
    }
}

// ---- final (unsorted path): [12][N] -> [N][24], LDS transpose ----
__global__ void __launch_bounds__(BLOCK)
assemble_kernel(const unsigned* __restrict__ lvl, float* __restrict__ out,
                int N)
{
    __shared__ float s_out[BLOCK * 25];
    const int t = threadIdx.x;
    const int n = blockIdx.x * BLOCK + t;

    if (n < N) {
#pragma unroll
        for (int l = 0; l < NLEV; ++l) {
            unsigned u = __builtin_nontemporal_load(&lvl[(long long)l * N + n]);
            s_out[t * 25 + 2 * l + 0] = lo2f(u);
            s_out[t * 25 + 2 * l + 1] = hi2f(u);
        }
    }
    __syncthreads();

    const long long base = (long long)blockIdx.x * (BLOCK * 24);
    const long long lim = (long long)N * 24;
#pragma unroll
    for (int k = 0; k < 24; ++k) {
        const int g = k * BLOCK + t;
        const long long gg = base + g;
        if (gg < lim) {
            const int nl = g / 24;
            const int j = g - nl * 24;
            __builtin_nontemporal_store(s_out[nl * 25 + j], &out[gg]);
        }
    }
}

// ---- fallback: fused single-kernel (ws too small for staging) ----
__global__ void __launch_bounds__(BLOCK, 4)
fused_kernel(const float* __restrict__ inp, const float2* __restrict__ table,
             float* __restrict__ out, int N)
{
    __shared__ float s_out[BLOCK * 25];
    const int t = threadIdx.x;
    const int n = blockIdx.x * BLOCK + t;

    if (n < N) {
        const float x = inp[n * 3 + 0];
        const float y = inp[n * 3 + 1];
        const float z = inp[n * 3 + 2];

#pragma unroll
        for (int l = 0; l < NLEV; ++l) {
            const int R = kRes[l];
            const bool HASH = (l >= 5);
            const float scale = (float)(R - 1);
            const float px = x * scale, py = y * scale, pz = z * scale;
            const float fx = floorf(px), fy = floorf(py), fz = floorf(pz);
            const float wx = px - fx, wy = py - fy, wz = pz - fz;
            const unsigned ix = (unsigned)fx, iy = (unsigned)fy,
                           iz = (unsigned)fz;
            unsigned x0, x1, y0, y1, z0, z1;
            if (HASH) {
                x0 = ix;      x1 = ix + 1u;
                y0 = iy * P1; y1 = y0 + P1;
                z0 = iz * P2; z1 = z0 + P2;
            } else {
                const unsigned Ru = (unsigned)R, R2 = Ru * Ru;
                x0 = ix;      x1 = ix + 1u;
                y0 = iy * Ru; y1 = y0 + Ru;
                z0 = iz * R2; z1 = z0 + R2;
            }
            unsigned idx[8];
            if (HASH) {
                idx[0] = (x0 ^ y0 ^ z0) & HMASK; idx[1] = (x1 ^ y0 ^ z0) & HMASK;
                idx[2] = (x0 ^ y1 ^ z0) & HMASK; idx[3] = (x1 ^ y1 ^ z0) & HMASK;
                idx[4] = (x0 ^ y0 ^ z1) & HMASK; idx[5] = (x1 ^ y0 ^ z1) & HMASK;
                idx[6] = (x0 ^ y1 ^ z1) & HMASK; idx[7] = (x1 ^ y1 ^ z1) & HMASK;
            } else {
                idx[0] = x0 + y0 + z0; idx[1] = x1 + y0 + z0;
                idx[2] = x0 + y1 + z0; idx[3] = x1 + y1 + z0;
                idx[4] = x0 + y0 + z1; idx[5] = x1 + y0 + z1;
                idx[6] = x0 + y1 + z1; idx[7] = x1 + y1 + z1;
            }
            const float w0x = 1.0f - wx, w0y = 1.0f - wy, w0z = 1.0f - wz;
            const float w00 = w0x * w0y, w10 = wx * w0y;
            const float w01 = w0x * wy,  w11 = wx * wy;
            const float wt[8] = {w00 * w0z, w10 * w0z, w01 * w0z, w11 * w0z,
                                 w00 * wz,  w10 * wz,  w01 * wz,  w11 * wz};
            float sx = 0.0f, sy = 0.0f;
#pragma unroll
            for (int c = 0; c < 8; ++c) {
                float2 e = table[kOff[l] + idx[c]];
                sx = fmaf(wt[c], e.x, sx);
                sy = fmaf(wt[c], e.y, sy);
            }
            s_out[t * 25 + 2 * l + 0] = sx;
            s_out[t * 25 + 2 * l + 1] = sy;
        }
    }
    __syncthreads();
    const long long base = (long long)blockIdx.x * (BLOCK * 24);
    const long long lim = (long long)N * 24;
#pragma unroll
    for (int k = 0; k < 24; ++k) {
        const int g = k * BLOCK + t;
        const long long gg = base + g;
        if (gg < lim) {
            const int nl = g / 24;
            const int j = g - nl * 24;
            out[gg] = s_out[nl * 25 + j];
        }
    }
}

extern "C" void kernel_launch(void* const* d_in, const int* in_sizes, int n_in,
                              void* d_out, int out_size, void* d_ws, size_t ws_size,
                              hipStream_t stream) {
    const float* inputs = (const float*)d_in[0];
    const float* embeddings = (const float*)d_in[1];
    // d_in[2]/d_in[3] (offsets/resolutions) are compile-time constants here.
    float* out = (float*)d_out;

    const int N = in_sizes[0] / 3;            // 2,000,000
    const int total = in_sizes[1] / 2;        // 4,078,528 table entries

    const size_t quad_bytes = (size_t)DENSE_A_END * 16;           // 2.34 MB
    const size_t pair4_bytes = (size_t)L4_SIZE * 8;               // 2.0 MB
    const size_t packed_bytes = (size_t)total * sizeof(unsigned); // 16.3 MB
    const size_t stage_bytes = (size_t)NLEV * N * sizeof(unsigned); // 96 MB
    const size_t sorted_bytes = (size_t)N * 16;                   // 32 MB
    const size_t hist_bytes = (size_t)NBUCK * 4;                  // 1 MB

    const int ngrid = (N + BLOCK - 1) / BLOCK;
    const int pairs = (N + 1) / 2;
    const int CB = (pairs + BLOCK - 1) / BLOCK;   // chunks per mega task

    const size_t mid_need = quad_bytes + pair4_bytes + packed_bytes + stage_bytes;
    const size_t full_need = mid_need + sorted_bytes + hist_bytes;

    if (ws_size >= full_need) {
        char* w = (char*)d_ws;
        u32x4* quad = (u32x4*)w;                  w += quad_bytes;
        u32x2* pair4 = (u32x2*)w;                 w += pair4_bytes;
        unsigned* packed = (unsigned*)w;          w += packed_bytes;
        unsigned* stage = (unsigned*)w;           w += stage_bytes;
        float4* sorted = (float4*)w;              w += sorted_bytes;
        unsigned* hist = (unsigned*)w;

        pack_all_kernel<<<(total + BLOCK - 1) / BLOCK, BLOCK, 0, stream>>>(
            (const float2*)embeddings, packed, quad, pair4, total);

        hipMemsetAsync(hist, 0, hist_bytes, stream);
        hist_kernel<<<ngrid, BLOCK, 0, stream>>>(inputs, hist, N);
        scan_kernel<<<1, 1024, 0, stream>>>(hist);
        scatter_kernel<<<ngrid, BLOCK, 0, stream>>>(inputs, hist, sorted, N);

        mega_kernel<1><<<9 * CB, BLOCK, 0, stream>>>(
            inputs, sorted, quad, pair4, packed, stage, N, CB);

        assemble_scatter_kernel<<<ngrid, BLOCK, 0, stream>>>(
            stage, sorted, out, N);
    } else if (ws_size >= mid_need) {
        char* w = (char*)d_ws;
        u32x4* quad = (u32x4*)w;                  w += quad_bytes;
        u32x2* pair4 = (u32x2*)w;                 w += pair4_bytes;
        unsigned* packed = (unsigned*)w;          w += packed_bytes;
        unsigned* stage = (unsigned*)w;

        pack_all_kernel<<<(total + BLOCK - 1) / BLOCK, BLOCK, 0, stream>>>(
            (const float2*)embeddings, packed, quad, pair4, total);
        mega_kernel<0><<<9 * CB, BLOCK, 0, stream>>>(
            inputs, nullptr, quad, pair4, packed, stage, N, CB);
        assemble_kernel<<<ngrid, BLOCK, 0, stream>>>(stage, out, N);
    } else {
        fused_kernel<<<ngrid, BLOCK, 0, stream>>>(
            inputs, (const float2*)embeddings, out, N);
    }
}

// Round 15
// 679.728 us; speedup vs baseline: 1.0396x; 1.0396x over previous
//
#include <hip/hip_runtime.h>
#include <hip/hip_fp16.h>

// Instant-NGP grid encoder, MI355X (gfx950).
// N=2,000,000 points [N,3] f32 in [0,1); 12 levels, F=2; out [N,24] f32.
// res: 16,23,32,46,64,92,128,184,256,368,512,736; hash iff r^3>2^19
// (levels 5..11, each exactly 2^19 entries -> & 0x7FFFF). Dense: no modulo.
//
// Round-15: sort kept (r14: mega 455->262us, transaction model confirmed),
// plumbing fixed:
//  * 3-pass multi-block scan (r14's single-block scan ~100+us on 1 CU).
//  * ONE fused kernel over sorted points (all 12 levels/thread): intra-wave
//    line merging is the win, not level-phasing; input read once via perm;
//    stage written point-major 48B/pt COALESCED.
//  * assemble by GATHER (rank[n] -> 48B stage row, ~1.5 transactions/pt)
//    + coalesced out writes via LDS transpose. r14's scatter writes were
//    partial-line-RMW bound (~200us).
//  Output values independent of atomic ordering -> deterministic.

namespace {
constexpr int NLEV = 12;
constexpr int BLOCK = 256;
constexpr int DENSE_A_END = 146368;   // levels 0..3
constexpr int L4_SIZE = 262144;       // level 4 (64^3)
constexpr int NBUCK = 262144;         // 64^3 Morton buckets
constexpr unsigned P1 = 2654435761u;
constexpr unsigned P2 = 805459861u;
constexpr unsigned HMASK = (1u << 19) - 1u;

__device__ __constant__ constexpr int kRes[NLEV] = {
    16, 23, 32, 46, 64, 92, 128, 184, 256, 368, 512, 736};
__device__ __constant__ constexpr int kOff[NLEV] = {
    0, 4096, 16264, 49032, 146368, 408512,
    932800, 1457088, 1981376, 2505664, 3029952, 3554240};

typedef unsigned u32x2 __attribute__((ext_vector_type(2)));
typedef unsigned u32x4 __attribute__((ext_vector_type(4)));

__device__ __forceinline__ unsigned pkh2(float a, float b) {
    __half2 h = __floats2half2_rn(a, b);
    return *reinterpret_cast<unsigned*>(&h);
}
__device__ __forceinline__ float lo2f(unsigned u) {
    __half2 h = *reinterpret_cast<__half2*>(&u);
    return __low2float(h);
}
__device__ __forceinline__ float hi2f(unsigned u) {
    __half2 h = *reinterpret_cast<__half2*>(&u);
    return __high2float(h);
}
__device__ __forceinline__ unsigned spread3(unsigned v) {
    v = (v | v << 16) & 0x030000FFu;
    v = (v | v << 8)  & 0x0300F00Fu;
    v = (v | v << 4)  & 0x030C30C3u;
    v = (v | v << 2)  & 0x09249249u;
    return v;
}
__device__ __forceinline__ unsigned morton6(float x, float y, float z) {
    unsigned ix = min(63u, (unsigned)(x * 64.0f));
    unsigned iy = min(63u, (unsigned)(y * 64.0f));
    unsigned iz = min(63u, (unsigned)(z * 64.0f));
    return spread3(ix) | (spread3(iy) << 1) | (spread3(iz) << 2);
}
}  // namespace

// ---- fused pre-pass: packed (all), quad (levels 0-3), pair4 (level 4) ----
__global__ void __launch_bounds__(BLOCK)
pack_all_kernel(const float2* __restrict__ emb,
                unsigned* __restrict__ packed,
                u32x4* __restrict__ quad,
                u32x2* __restrict__ pair4, int total)
{
    int i = blockIdx.x * BLOCK + threadIdx.x;
    if (i >= total) return;
    float2 v = emb[i];
    packed[i] = pkh2(v.x, v.y);
    if (i < DENSE_A_END) {
        int R = (i < 4096) ? 16 : (i < 16264) ? 23 : (i < 49032) ? 32 : 46;
        float2 e1 = emb[i + 1];
        float2 e2 = emb[i + R];
        float2 e3 = emb[i + R + 1];
        u32x4 q;
        q.x = pkh2(v.x, v.y);   q.y = pkh2(e1.x, e1.y);
        q.z = pkh2(e2.x, e2.y); q.w = pkh2(e3.x, e3.y);
        quad[i] = q;
    }
    if (i < L4_SIZE) {
        int g = DENSE_A_END + i;
        float2 a = emb[g];
        float2 b = emb[g + 1];
        u32x2 o; o.x = pkh2(a.x, a.y); o.y = pkh2(b.x, b.y);
        pair4[i] = o;
    }
}

// ---- sort 1: bucket histogram ----
__global__ void __launch_bounds__(BLOCK)
hist_kernel(const float* __restrict__ inp, unsigned* __restrict__ hist, int N)
{
    int n = blockIdx.x * BLOCK + threadIdx.x;
    if (n >= N) return;
    const float x = inp[3 * n + 0];
    const float y = inp[3 * n + 1];
    const float z = inp[3 * n + 2];
    atomicAdd(&hist[morton6(x, y, z)], 1u);
}

// ---- sort 2a: per-segment sums (256 segments x 1024 buckets) ----
__global__ void __launch_bounds__(BLOCK)
scanA_kernel(const unsigned* __restrict__ hist, unsigned* __restrict__ segsum)
{
    __shared__ unsigned s[BLOCK];
    const int b = blockIdx.x, t = threadIdx.x;
    const int base = b * 1024 + t * 4;
    unsigned sum = hist[base] + hist[base + 1] + hist[base + 2] + hist[base + 3];
    s[t] = sum;
    __syncthreads();
    for (int off = BLOCK / 2; off > 0; off >>= 1) {
        if (t < off) s[t] += s[t + off];
        __syncthreads();
    }
    if (t == 0) segsum[b] = s[0];
}

// ---- sort 2b: exclusive scan of 256 segment sums ----
__global__ void __launch_bounds__(BLOCK)
scanB_kernel(unsigned* __restrict__ segsum)
{
    __shared__ unsigned s[BLOCK];
    const int t = threadIdx.x;
    unsigned own = segsum[t];
    s[t] = own;
    __syncthreads();
    for (int off = 1; off < BLOCK; off <<= 1) {
        unsigned v = (t >= off) ? s[t - off] : 0u;
        __syncthreads();
        s[t] += v;
        __syncthreads();
    }
    segsum[t] = s[t] - own;   // exclusive
}

// ---- sort 2c: per-segment exclusive offsets (in-place hist -> offsets) ----
__global__ void __launch_bounds__(BLOCK)
scanC_kernel(unsigned* __restrict__ hist, const unsigned* __restrict__ segsum)
{
    __shared__ unsigned s[BLOCK];
    const int b = blockIdx.x, t = threadIdx.x;
    const int base = b * 1024 + t * 4;
    unsigned h0 = hist[base], h1 = hist[base + 1];
    unsigned h2 = hist[base + 2], h3 = hist[base + 3];
    unsigned mysum = h0 + h1 + h2 + h3;
    s[t] = mysum;
    __syncthreads();
    for (int off = 1; off < BLOCK; off <<= 1) {
        unsigned v = (t >= off) ? s[t - off] : 0u;
        __syncthreads();
        s[t] += v;
        __syncthreads();
    }
    unsigned run = segsum[b] + (s[t] - mysum);
    hist[base] = run;     run += h0;
    hist[base + 1] = run; run += h1;
    hist[base + 2] = run; run += h2;
    hist[base + 3] = run;
}

// ---- sort 3: permutation (perm[pos]=orig, rank[orig]=pos) ----
__global__ void __launch_bounds__(BLOCK)
scatter_kernel(const float* __restrict__ inp, unsigned* __restrict__ offs,
               unsigned* __restrict__ perm, unsigned* __restrict__ rank, int N)
{
    int n = blockIdx.x * BLOCK + threadIdx.x;
    if (n >= N) return;
    const float x = inp[3 * n + 0];
    const float y = inp[3 * n + 1];
    const float z = inp[3 * n + 2];
    unsigned pos = atomicAdd(&offs[morton6(x, y, z)], 1u);
    perm[pos] = (unsigned)n;
    rank[n] = pos;
}

// ---- hash level encode (aligned x-pair words on 4B packed table) ----
__device__ __forceinline__ unsigned
encode_hash_rt(float x, float y, float z, const unsigned* __restrict__ pt,
               float scale)
{
    const float px = x * scale, py = y * scale, pz = z * scale;
    const float fx = floorf(px), fy = floorf(py), fz = floorf(pz);
    const float rx = px - fx, ry = py - fy, rz = pz - fz;
    const unsigned ix = (unsigned)fx, iy = (unsigned)fy, iz = (unsigned)fz;
    const unsigned yA = iy * P1, yB = yA + P1;
    const unsigned zA = iz * P2, zB = zA + P2;
    const unsigned h00 = (ix ^ yA ^ zA) & HMASK;
    const unsigned h10 = (ix ^ yB ^ zA) & HMASK;
    const unsigned h01 = (ix ^ yA ^ zB) & HMASK;
    const unsigned h11 = (ix ^ yB ^ zB) & HMASK;

    const u32x2* pt2 = reinterpret_cast<const u32x2*>(pt);
    const u32x2 q00 = pt2[h00 >> 1];
    const u32x2 q10 = pt2[h10 >> 1];
    const u32x2 q01 = pt2[h01 >> 1];
    const u32x2 q11 = pt2[h11 >> 1];

    unsigned e00 = (h00 & 1) ? q00.y : q00.x;
    unsigned e10 = (h10 & 1) ? q10.y : q10.x;
    unsigned e01 = (h01 & 1) ? q01.y : q01.x;
    unsigned e11 = (h11 & 1) ? q11.y : q11.x;
    unsigned f00 = (h00 & 1) ? q00.x : q00.y;
    unsigned f10 = (h10 & 1) ? q10.x : q10.y;
    unsigned f01 = (h01 & 1) ? q01.x : q01.y;
    unsigned f11 = (h11 & 1) ? q11.x : q11.y;

    if (ix & 1u) {  // odd ix: sibling word is ix-1; need real ix+1 entries
        const unsigned xo = ix + 1u;
        f00 = pt[(xo ^ yA ^ zA) & HMASK];
        f10 = pt[(xo ^ yB ^ zA) & HMASK];
        f01 = pt[(xo ^ yA ^ zB) & HMASK];
        f11 = pt[(xo ^ yB ^ zB) & HMASK];
    }

    const float wx0 = 1.0f - rx, wx1 = rx;
    const float wy0 = 1.0f - ry, wy1 = ry;
    const float wz0 = 1.0f - rz, wz1 = rz;
    const float w00 = wy0 * wz0, w10 = wy1 * wz0;
    const float w01 = wy0 * wz1, w11 = wy1 * wz1;
    float sx = 0.0f, sy = 0.0f;
    sx = fmaf(w00 * wx0, lo2f(e00), fmaf(w00 * wx1, lo2f(f00), sx));
    sy = fmaf(w00 * wx0, hi2f(e00), fmaf(w00 * wx1, hi2f(f00), sy));
    sx = fmaf(w10 * wx0, lo2f(e10), fmaf(w10 * wx1, lo2f(f10), sx));
    sy = fmaf(w10 * wx0, hi2f(e10), fmaf(w10 * wx1, hi2f(f10), sy));
    sx = fmaf(w01 * wx0, lo2f(e01), fmaf(w01 * wx1, lo2f(f01), sx));
    sy = fmaf(w01 * wx0, hi2f(e01), fmaf(w01 * wx1, hi2f(f01), sy));
    sx = fmaf(w11 * wx0, lo2f(e11), fmaf(w11 * wx1, lo2f(f11), sx));
    sy = fmaf(w11 * wx0, hi2f(e11), fmaf(w11 * wx1, hi2f(f11), sy));
    return pkh2(sx, sy);
}

// ---- compute all 12 levels for one point -> res[12] fp16x2 words ----
__device__ __forceinline__ void
encode_point(float x, float y, float z,
             const u32x4* __restrict__ quad,
             const u32x2* __restrict__ pair4,
             const unsigned* __restrict__ packed,
             unsigned res[NLEV])
{
    // dense levels 0..3: quad gathers (16B entries)
#pragma unroll
    for (int l = 0; l < 4; ++l) {
        const unsigned R = (unsigned)kRes[l];
        const unsigned R2 = R * R;
        const float scale = (float)(kRes[l] - 1);
        const u32x4* qt = quad + kOff[l];
        const float px = x * scale, py = y * scale, pz = z * scale;
        const float fx = floorf(px), fy = floorf(py), fz = floorf(pz);
        const float rx = px - fx, ry = py - fy, rz = pz - fz;
        const unsigned ix = (unsigned)fx, iy = (unsigned)fy, iz = (unsigned)fz;
        const unsigned base = ix + iy * R + iz * R2;
        const u32x4 q0 = qt[base];
        const u32x4 q1 = qt[base + R2];
        const float wx0 = 1.0f - rx, wx1 = rx;
        const float wy0 = 1.0f - ry, wy1 = ry;
        const float wz0 = 1.0f - rz, wz1 = rz;
        const float ex00 = wx0 * lo2f(q0.x) + wx1 * lo2f(q0.y);
        const float ey00 = wx0 * hi2f(q0.x) + wx1 * hi2f(q0.y);
        const float ex10 = wx0 * lo2f(q0.z) + wx1 * lo2f(q0.w);
        const float ey10 = wx0 * hi2f(q0.z) + wx1 * hi2f(q0.w);
        const float ex01 = wx0 * lo2f(q1.x) + wx1 * lo2f(q1.y);
        const float ey01 = wx0 * hi2f(q1.x) + wx1 * hi2f(q1.y);
        const float ex11 = wx0 * lo2f(q1.z) + wx1 * lo2f(q1.w);
        const float ey11 = wx0 * hi2f(q1.z) + wx1 * hi2f(q1.w);
        const float sx = wz0 * (wy0 * ex00 + wy1 * ex10) +
                         wz1 * (wy0 * ex01 + wy1 * ex11);
        const float sy = wz0 * (wy0 * ey00 + wy1 * ey10) +
                         wz1 * (wy0 * ey01 + wy1 * ey11);
        res[l] = pkh2(sx, sy);
    }
    // dense level 4: pair gathers (8B entries)
    {
        constexpr unsigned R = 64, R2 = 4096;
        constexpr float scale = 63.0f;
        const float px = x * scale, py = y * scale, pz = z * scale;
        const float fx = floorf(px), fy = floorf(py), fz = floorf(pz);
        const float rx = px - fx, ry = py - fy, rz = pz - fz;
        const unsigned ix = (unsigned)fx, iy = (unsigned)fy, iz = (unsigned)fz;
        const unsigned base = ix + iy * R + iz * R2;
        const u32x2 q00 = pair4[base];
        const u32x2 q10 = pair4[base + R];
        const u32x2 q01 = pair4[base + R2];
        const u32x2 q11 = pair4[base + R2 + R];
        const float wx0 = 1.0f - rx, wx1 = rx;
        const float wy0 = 1.0f - ry, wy1 = ry;
        const float wz0 = 1.0f - rz, wz1 = rz;
        const float w00 = wy0 * wz0, w10 = wy1 * wz0;
        const float w01 = wy0 * wz1, w11 = wy1 * wz1;
        float sx = 0.0f, sy = 0.0f;
        sx = fmaf(w00 * wx0, lo2f(q00.x), fmaf(w00 * wx1, lo2f(q00.y), sx));
        sy = fmaf(w00 * wx0, hi2f(q00.x), fmaf(w00 * wx1, hi2f(q00.y), sy));
        sx = fmaf(w10 * wx0, lo2f(q10.x), fmaf(w10 * wx1, lo2f(q10.y), sx));
        sy = fmaf(w10 * wx0, hi2f(q10.x), fmaf(w10 * wx1, hi2f(q10.y), sy));
        sx = fmaf(w01 * wx0, lo2f(q01.x), fmaf(w01 * wx1, lo2f(q01.y), sx));
        sy = fmaf(w01 * wx0, hi2f(q01.x), fmaf(w01 * wx1, hi2f(q01.y), sy));
        sx = fmaf(w11 * wx0, lo2f(q11.x), fmaf(w11 * wx1, lo2f(q11.y), sx));
        sy = fmaf(w11 * wx0, hi2f(q11.x), fmaf(w11 * wx1, hi2f(q11.y), sy));
        res[4] = pkh2(sx, sy);
    }
    // hash levels 5..11
#pragma unroll
    for (int l = 5; l < NLEV; ++l) {
        const float scale = (float)(kRes[l] - 1);
        res[l] = encode_hash_rt(x, y, z, packed + kOff[l], scale);
    }
}

// ---- fused over sorted order: stage[p][12] u32, coalesced 48B rows ----
__global__ void __launch_bounds__(BLOCK)
fused_sorted_kernel(const float* __restrict__ inp,
                    const unsigned* __restrict__ perm,
                    const u32x4* __restrict__ quad,
                    const u32x2* __restrict__ pair4,
                    const unsigned* __restrict__ packed,
                    u32x4* __restrict__ stage, int N)
{
    const int g = blockIdx.x * BLOCK + threadIdx.x;
    const int p0 = 2 * g;
    if (p0 >= N) return;
    const bool two = (p0 + 1 < N);

    const unsigned o0 = perm[p0];
    const unsigned o1 = two ? perm[p0 + 1] : o0;
    const float x0 = inp[3 * o0 + 0], y0 = inp[3 * o0 + 1],
                z0 = inp[3 * o0 + 2];
    const float x1 = inp[3 * o1 + 0], y1 = inp[3 * o1 + 1],
                z1 = inp[3 * o1 + 2];

    unsigned r0[NLEV], r1[NLEV];
    encode_point(x0, y0, z0, quad, pair4, packed, r0);
    encode_point(x1, y1, z1, quad, pair4, packed, r1);

    u32x4 a, b, c;
    a.x = r0[0]; a.y = r0[1]; a.z = r0[2];  a.w = r0[3];
    b.x = r0[4]; b.y = r0[5]; b.z = r0[6];  b.w = r0[7];
    c.x = r0[8]; c.y = r0[9]; c.z = r0[10]; c.w = r0[11];
    stage[3LL * p0 + 0] = a;
    stage[3LL * p0 + 1] = b;
    stage[3LL * p0 + 2] = c;
    if (two) {
        a.x = r1[0]; a.y = r1[1]; a.z = r1[2];  a.w = r1[3];
        b.x = r1[4]; b.y = r1[5]; b.z = r1[6];  b.w = r1[7];
        c.x = r1[8]; c.y = r1[9]; c.z = r1[10]; c.w = r1[11];
        stage[3LL * p0 + 3] = a;
        stage[3LL * p0 + 4] = b;
        stage[3LL * p0 + 5] = c;
    }
}

// ---- assemble by gather: out[n] <- stage[rank[n]], coalesced out ----
__global__ void __launch_bounds__(BLOCK)
assemble_gather_kernel(const u32x4* __restrict__ stage,
                       const unsigned* __restrict__ rank,
                       float* __restrict__ out, int N)
{
    __shared__ float s_out[BLOCK * 25];
    const int t = threadIdx.x;
    const int n = blockIdx.x * BLOCK + t;

    if (n < N) {
        const unsigned pos = rank[n];
        const u32x4 qa = stage[3LL * pos + 0];
        const u32x4 qb = stage[3LL * pos + 1];
        const u32x4 qc = stage[3LL * pos + 2];
        unsigned r[NLEV] = {qa.x, qa.y, qa.z, qa.w,
                            qb.x, qb.y, qb.z, qb.w,
                            qc.x, qc.y, qc.z, qc.w};
#pragma unroll
        for (int l = 0; l < NLEV; ++l) {
            s_out[t * 25 + 2 * l + 0] = lo2f(r[l]);
            s_out[t * 25 + 2 * l + 1] = hi2f(r[l]);
        }
    }
    __syncthreads();

    const long long base = (long long)blockIdx.x * (BLOCK * 24);
    const long long lim = (long long)N * 24;
#pragma unroll
    for (int k = 0; k < 24; ++k) {
        const int g = k * BLOCK + t;
        const long long gg = base + g;
        if (gg < lim) {
            const int nl = g / 24;   // magic-mul division
            const int j = g - nl * 24;
            __builtin_nontemporal_store(s_out[nl * 25 + j], &out[gg]);
        }
    }
}

// ---- fallback: fused single-kernel on f32 table (ws too small) ----
__global__ void __launch_bounds__(BLOCK, 4)
fused_kernel(const float* __restrict__ inp, const float2* __restrict__ table,
             float* __restrict__ out, int N)
{
    __shared__ float s_out[BLOCK * 25];
    const int t = threadIdx.x;
    const int n = blockIdx.x * BLOCK + t;

    if (n < N) {
        const float x = inp[n * 3 + 0];
        const float y = inp[n * 3 + 1];
        const float z = inp[n * 3 + 2];

#pragma unroll
        for (int l = 0; l < NLEV; ++l) {
            const int R = kRes[l];
            const bool HASH = (l >= 5);
            const float scale = (float)(R - 1);
            const float px = x * scale, py = y * scale, pz = z * scale;
            const float fx = floorf(px), fy = floorf(py), fz = floorf(pz);
            const float wx = px - fx, wy = py - fy, wz = pz - fz;
            const unsigned ix = (unsigned)fx, iy = (unsigned)fy,
                           iz = (unsigned)fz;
            unsigned x0, x1, y0, y1, z0, z1;
            if (HASH) {
                x0 = ix;      x1 = ix + 1u;
                y0 = iy * P1; y1 = y0 + P1;
                z0 = iz * P2; z1 = z0 + P2;
            } else {
                const unsigned Ru = (unsigned)R, R2 = Ru * Ru;
                x0 = ix;      x1 = ix + 1u;
                y0 = iy * Ru; y1 = y0 + Ru;
                z0 = iz * R2; z1 = z0 + R2;
            }
            unsigned idx[8];
            if (HASH) {
                idx[0] = (x0 ^ y0 ^ z0) & HMASK; idx[1] = (x1 ^ y0 ^ z0) & HMASK;
                idx[2] = (x0 ^ y1 ^ z0) & HMASK; idx[3] = (x1 ^ y1 ^ z0) & HMASK;
                idx[4] = (x0 ^ y0 ^ z1) & HMASK; idx[5] = (x1 ^ y0 ^ z1) & HMASK;
                idx[6] = (x0 ^ y1 ^ z1) & HMASK; idx[7] = (x1 ^ y1 ^ z1) & HMASK;
            } else {
                idx[0] = x0 + y0 + z0; idx[1] = x1 + y0 + z0;
                idx[2] = x0 + y1 + z0; idx[3] = x1 + y1 + z0;
                idx[4] = x0 + y0 + z1; idx[5] = x1 + y0 + z1;
                idx[6] = x0 + y1 + z1; idx[7] = x1 + y1 + z1;
            }
            const float w0x = 1.0f - wx, w0y = 1.0f - wy, w0z = 1.0f - wz;
            const float w00 = w0x * w0y, w10 = wx * w0y;
            const float w01 = w0x * wy,  w11 = wx * wy;
            const float wt[8] = {w00 * w0z, w10 * w0z, w01 * w0z, w11 * w0z,
                                 w00 * wz,  w10 * wz,  w01 * wz,  w11 * wz};
            float sx = 0.0f, sy = 0.0f;
#pragma unroll
            for (int c = 0; c < 8; ++c) {
                float2 e = table[kOff[l] + idx[c]];
                sx = fmaf(wt[c], e.x, sx);
                sy = fmaf(wt[c], e.y, sy);
            }
            s_out[t * 25 + 2 * l + 0] = sx;
            s_out[t * 25 + 2 * l + 1] = sy;
        }
    }
    __syncthreads();
    const long long base = (long long)blockIdx.x * (BLOCK * 24);
    const long long lim = (long long)N * 24;
#pragma unroll
    for (int k = 0; k < 24; ++k) {
        const int g = k * BLOCK + t;
        const long long gg = base + g;
        if (gg < lim) {
            const int nl = g / 24;
            const int j = g - nl * 24;
            out[gg] = s_out[nl * 25 + j];
        }
    }
}

extern "C" void kernel_launch(void* const* d_in, const int* in_sizes, int n_in,
                              void* d_out, int out_size, void* d_ws, size_t ws_size,
                              hipStream_t stream) {
    const float* inputs = (const float*)d_in[0];
    const float* embeddings = (const float*)d_in[1];
    // d_in[2]/d_in[3] (offsets/resolutions) are compile-time constants here.
    float* out = (float*)d_out;

    const int N = in_sizes[0] / 3;            // 2,000,000
    const int total = in_sizes[1] / 2;        // 4,078,528 table entries

    const size_t quad_bytes = (size_t)DENSE_A_END * 16;           // 2.34 MB
    const size_t pair4_bytes = (size_t)L4_SIZE * 8;               // 2.0 MB
    const size_t packed_bytes = (size_t)total * sizeof(unsigned); // 16.3 MB
    const size_t stage_bytes = (size_t)N * 48;                    // 96 MB
    const size_t perm_bytes = (size_t)N * 4;                      // 8 MB
    const size_t rank_bytes = (size_t)N * 4;                      // 8 MB
    const size_t hist_bytes = (size_t)NBUCK * 4;                  // 1 MB
    const size_t seg_bytes = 256 * 4;

    const int ngrid = (N + BLOCK - 1) / BLOCK;
    const int pgrid = (total + BLOCK - 1) / BLOCK;
    const int pairs = (N + 1) / 2;
    const int hgrid = (pairs + BLOCK - 1) / BLOCK;

    const size_t full_need = quad_bytes + pair4_bytes + packed_bytes +
                             stage_bytes + perm_bytes + rank_bytes +
                             hist_bytes + seg_bytes;   // ~133.8 MB

    if (ws_size >= full_need) {
        char* w = (char*)d_ws;
        u32x4* quad = (u32x4*)w;                  w += quad_bytes;
        u32x2* pair4 = (u32x2*)w;                 w += pair4_bytes;
        unsigned* packed = (unsigned*)w;          w += packed_bytes;
        u32x4* stage = (u32x4*)w;                 w += stage_bytes;
        unsigned* perm = (unsigned*)w;            w += perm_bytes;
        unsigned* rank = (unsigned*)w;            w += rank_bytes;
        unsigned* hist = (unsigned*)w;            w += hist_bytes;
        unsigned* segsum = (unsigned*)w;

        pack_all_kernel<<<pgrid, BLOCK, 0, stream>>>(
            (const float2*)embeddings, packed, quad, pair4, total);

        hipMemsetAsync(hist, 0, hist_bytes, stream);
        hist_kernel<<<ngrid, BLOCK, 0, stream>>>(inputs, hist, N);
        scanA_kernel<<<256, BLOCK, 0, stream>>>(hist, segsum);
        scanB_kernel<<<1, BLOCK, 0, stream>>>(segsum);
        scanC_kernel<<<256, BLOCK, 0, stream>>>(hist, segsum);
        scatter_kernel<<<ngrid, BLOCK, 0, stream>>>(inputs, hist, perm, rank, N);

        fused_sorted_kernel<<<hgrid, BLOCK, 0, stream>>>(
            inputs, perm, quad, pair4, packed, stage, N);

        assemble_gather_kernel<<<ngrid, BLOCK, 0, stream>>>(
            stage, rank, out, N);
    } else {
        fused_kernel<<<ngrid, BLOCK, 0, stream>>>(
            inputs, (const float2*)embeddings, out, N);
    }
}

// Round 16
// 621.351 us; speedup vs baseline: 1.1372x; 1.0940x over previous
//
#include <hip/hip_runtime.h>
#include <hip/hip_fp16.h>

// Instant-NGP grid encoder, MI355X (gfx950).
// N=2,000,000 points [N,3] f32 in [0,1); 12 levels, F=2; out [N,24] f32.
// res: 16,23,32,46,64,92,128,184,256,368,512,736; hash iff r^3>2^19
// (levels 5..11, each exactly 2^19 entries -> & 0x7FFFF). Dense: no modulo.
//
// Round-16: sorted single-pass encoder with LDS result buffering.
//   r14 proved sorted gathers run at 262us (level-phased mega); r15's
//   all-level fused failed from VGPR 204 (occ 11%) + 12x4B assemble gathers.
//   Fixes: (1) per-level results go to LDS s[t*13+l] (hash levels in a
//   ROLLED loop, runtime consts -> ~80 VGPR); block then writes point-major
//   48B rows COALESCED (nt, full lines). (2) assemble gathers ONE 48B row
//   per point via rank[n] (~1.5 lines/pt, 3M fills vs r15's 24M) + LDS
//   transpose + coalesced nt out. ws = 133.8MB (= r15 proven footprint).

namespace {
constexpr int NLEV = 12;
constexpr int BLOCK = 256;
constexpr int DENSE_A_END = 146368;   // levels 0..3
constexpr int L4_SIZE = 262144;       // level 4 (64^3)
constexpr int NBUCK = 262144;         // 64^3 Morton buckets
constexpr unsigned P1 = 2654435761u;
constexpr unsigned P2 = 805459861u;
constexpr unsigned HMASK = (1u << 19) - 1u;

__device__ __constant__ constexpr int kRes[NLEV] = {
    16, 23, 32, 46, 64, 92, 128, 184, 256, 368, 512, 736};
__device__ __constant__ constexpr int kOff[NLEV] = {
    0, 4096, 16264, 49032, 146368, 408512,
    932800, 1457088, 1981376, 2505664, 3029952, 3554240};

typedef unsigned u32x2 __attribute__((ext_vector_type(2)));
typedef unsigned u32x4 __attribute__((ext_vector_type(4)));

__device__ __forceinline__ unsigned pkh2(float a, float b) {
    __half2 h = __floats2half2_rn(a, b);
    return *reinterpret_cast<unsigned*>(&h);
}
__device__ __forceinline__ float lo2f(unsigned u) {
    __half2 h = *reinterpret_cast<__half2*>(&u);
    return __low2float(h);
}
__device__ __forceinline__ float hi2f(unsigned u) {
    __half2 h = *reinterpret_cast<__half2*>(&u);
    return __high2float(h);
}
__device__ __forceinline__ unsigned spread3(unsigned v) {
    v = (v | v << 16) & 0x030000FFu;
    v = (v | v << 8)  & 0x0300F00Fu;
    v = (v | v << 4)  & 0x030C30C3u;
    v = (v | v << 2)  & 0x09249249u;
    return v;
}
__device__ __forceinline__ unsigned morton6(float x, float y, float z) {
    unsigned ix = min(63u, (unsigned)(x * 64.0f));
    unsigned iy = min(63u, (unsigned)(y * 64.0f));
    unsigned iz = min(63u, (unsigned)(z * 64.0f));
    return spread3(ix) | (spread3(iy) << 1) | (spread3(iz) << 2);
}
}  // namespace

// ---- fused pre-pass: packed (all), quad (levels 0-3), pair4 (level 4) ----
__global__ void __launch_bounds__(BLOCK)
pack_all_kernel(const float2* __restrict__ emb,
                unsigned* __restrict__ packed,
                u32x4* __restrict__ quad,
                u32x2* __restrict__ pair4, int total)
{
    int i = blockIdx.x * BLOCK + threadIdx.x;
    if (i >= total) return;
    float2 v = emb[i];
    packed[i] = pkh2(v.x, v.y);
    if (i < DENSE_A_END) {
        int R = (i < 4096) ? 16 : (i < 16264) ? 23 : (i < 49032) ? 32 : 46;
        float2 e1 = emb[i + 1];
        float2 e2 = emb[i + R];
        float2 e3 = emb[i + R + 1];
        u32x4 q;
        q.x = pkh2(v.x, v.y);   q.y = pkh2(e1.x, e1.y);
        q.z = pkh2(e2.x, e2.y); q.w = pkh2(e3.x, e3.y);
        quad[i] = q;
    }
    if (i < L4_SIZE) {
        int g = DENSE_A_END + i;
        float2 a = emb[g];
        float2 b = emb[g + 1];
        u32x2 o; o.x = pkh2(a.x, a.y); o.y = pkh2(b.x, b.y);
        pair4[i] = o;
    }
}

// ---- sort 1: bucket histogram ----
__global__ void __launch_bounds__(BLOCK)
hist_kernel(const float* __restrict__ inp, unsigned* __restrict__ hist, int N)
{
    int n = blockIdx.x * BLOCK + threadIdx.x;
    if (n >= N) return;
    const float x = inp[3 * n + 0];
    const float y = inp[3 * n + 1];
    const float z = inp[3 * n + 2];
    atomicAdd(&hist[morton6(x, y, z)], 1u);
}

// ---- sort 2a: per-segment sums (256 segments x 1024 buckets) ----
__global__ void __launch_bounds__(BLOCK)
scanA_kernel(const unsigned* __restrict__ hist, unsigned* __restrict__ segsum)
{
    __shared__ unsigned s[BLOCK];
    const int b = blockIdx.x, t = threadIdx.x;
    const int base = b * 1024 + t * 4;
    unsigned sum = hist[base] + hist[base + 1] + hist[base + 2] + hist[base + 3];
    s[t] = sum;
    __syncthreads();
    for (int off = BLOCK / 2; off > 0; off >>= 1) {
        if (t < off) s[t] += s[t + off];
        __syncthreads();
    }
    if (t == 0) segsum[b] = s[0];
}

// ---- sort 2b: exclusive scan of 256 segment sums ----
__global__ void __launch_bounds__(BLOCK)
scanB_kernel(unsigned* __restrict__ segsum)
{
    __shared__ unsigned s[BLOCK];
    const int t = threadIdx.x;
    unsigned own = segsum[t];
    s[t] = own;
    __syncthreads();
    for (int off = 1; off < BLOCK; off <<= 1) {
        unsigned v = (t >= off) ? s[t - off] : 0u;
        __syncthreads();
        s[t] += v;
        __syncthreads();
    }
    segsum[t] = s[t] - own;   // exclusive
}

// ---- sort 2c: per-segment exclusive offsets (in-place hist -> offsets) ----
__global__ void __launch_bounds__(BLOCK)
scanC_kernel(unsigned* __restrict__ hist, const unsigned* __restrict__ segsum)
{
    __shared__ unsigned s[BLOCK];
    const int b = blockIdx.x, t = threadIdx.x;
    const int base = b * 1024 + t * 4;
    unsigned h0 = hist[base], h1 = hist[base + 1];
    unsigned h2 = hist[base + 2], h3 = hist[base + 3];
    unsigned mysum = h0 + h1 + h2 + h3;
    s[t] = mysum;
    __syncthreads();
    for (int off = 1; off < BLOCK; off <<= 1) {
        unsigned v = (t >= off) ? s[t - off] : 0u;
        __syncthreads();
        s[t] += v;
        __syncthreads();
    }
    unsigned run = segsum[b] + (s[t] - mysum);
    hist[base] = run;     run += h0;
    hist[base + 1] = run; run += h1;
    hist[base + 2] = run; run += h2;
    hist[base + 3] = run;
}

// ---- sort 3: permutation (perm[pos]=orig, rank[orig]=pos) ----
__global__ void __launch_bounds__(BLOCK)
scatter_kernel(const float* __restrict__ inp, unsigned* __restrict__ offs,
               unsigned* __restrict__ perm, unsigned* __restrict__ rank, int N)
{
    int n = blockIdx.x * BLOCK + threadIdx.x;
    if (n >= N) return;
    const float x = inp[3 * n + 0];
    const float y = inp[3 * n + 1];
    const float z = inp[3 * n + 2];
    unsigned pos = atomicAdd(&offs[morton6(x, y, z)], 1u);
    perm[pos] = (unsigned)n;
    rank[n] = pos;
}

// ---- hash level encode (aligned x-pair words on 4B packed table) ----
__device__ __forceinline__ unsigned
encode_hash_rt(float x, float y, float z, const unsigned* __restrict__ pt,
               float scale)
{
    const float px = x * scale, py = y * scale, pz = z * scale;
    const float fx = floorf(px), fy = floorf(py), fz = floorf(pz);
    const float rx = px - fx, ry = py - fy, rz = pz - fz;
    const unsigned ix = (unsigned)fx, iy = (unsigned)fy, iz = (unsigned)fz;
    const unsigned yA = iy * P1, yB = yA + P1;
    const unsigned zA = iz * P2, zB = zA + P2;
    const unsigned h00 = (ix ^ yA ^ zA) & HMASK;
    const unsigned h10 = (ix ^ yB ^ zA) & HMASK;
    const unsigned h01 = (ix ^ yA ^ zB) & HMASK;
    const unsigned h11 = (ix ^ yB ^ zB) & HMASK;

    const u32x2* pt2 = reinterpret_cast<const u32x2*>(pt);
    const u32x2 q00 = pt2[h00 >> 1];
    const u32x2 q10 = pt2[h10 >> 1];
    const u32x2 q01 = pt2[h01 >> 1];
    const u32x2 q11 = pt2[h11 >> 1];

    unsigned e00 = (h00 & 1) ? q00.y : q00.x;
    unsigned e10 = (h10 & 1) ? q10.y : q10.x;
    unsigned e01 = (h01 & 1) ? q01.y : q01.x;
    unsigned e11 = (h11 & 1) ? q11.y : q11.x;
    unsigned f00 = (h00 & 1) ? q00.x : q00.y;
    unsigned f10 = (h10 & 1) ? q10.x : q10.y;
    unsigned f01 = (h01 & 1) ? q01.x : q01.y;
    unsigned f11 = (h11 & 1) ? q11.x : q11.y;

    if (ix & 1u) {  // odd ix: sibling word is ix-1; need real ix+1 entries
        const unsigned xo = ix + 1u;
        f00 = pt[(xo ^ yA ^ zA) & HMASK];
        f10 = pt[(xo ^ yB ^ zA) & HMASK];
        f01 = pt[(xo ^ yA ^ zB) & HMASK];
        f11 = pt[(xo ^ yB ^ zB) & HMASK];
    }

    const float wx0 = 1.0f - rx, wx1 = rx;
    const float wy0 = 1.0f - ry, wy1 = ry;
    const float wz0 = 1.0f - rz, wz1 = rz;
    const float w00 = wy0 * wz0, w10 = wy1 * wz0;
    const float w01 = wy0 * wz1, w11 = wy1 * wz1;
    float sx = 0.0f, sy = 0.0f;
    sx = fmaf(w00 * wx0, lo2f(e00), fmaf(w00 * wx1, lo2f(f00), sx));
    sy = fmaf(w00 * wx0, hi2f(e00), fmaf(w00 * wx1, hi2f(f00), sy));
    sx = fmaf(w10 * wx0, lo2f(e10), fmaf(w10 * wx1, lo2f(f10), sx));
    sy = fmaf(w10 * wx0, hi2f(e10), fmaf(w10 * wx1, hi2f(f10), sy));
    sx = fmaf(w01 * wx0, lo2f(e01), fmaf(w01 * wx1, lo2f(f01), sx));
    sy = fmaf(w01 * wx0, hi2f(e01), fmaf(w01 * wx1, hi2f(f01), sy));
    sx = fmaf(w11 * wx0, lo2f(e11), fmaf(w11 * wx1, lo2f(f11), sx));
    sy = fmaf(w11 * wx0, hi2f(e11), fmaf(w11 * wx1, hi2f(f11), sy));
    return pkh2(sx, sy);
}

// ---- fused over sorted order, LDS-buffered, point-major 48B rows ----
__global__ void __launch_bounds__(BLOCK)
fused_pm_kernel(const float* __restrict__ inp,
                const unsigned* __restrict__ perm,
                const u32x4* __restrict__ quad,
                const u32x2* __restrict__ pair4,
                const unsigned* __restrict__ packed,
                unsigned* __restrict__ pm_u32, int N)
{
    __shared__ unsigned s[BLOCK * 13];   // [row][level], stride 13
    const int t = threadIdx.x;
    const int n = blockIdx.x * BLOCK + t;   // sorted position

    if (n < N) {
        const unsigned orig = perm[n];
        const float x = inp[3 * orig + 0];
        const float y = inp[3 * orig + 1];
        const float z = inp[3 * orig + 2];

        // dense levels 0..3: quad gathers (16B entries), unrolled
#pragma unroll
        for (int l = 0; l < 4; ++l) {
            const unsigned R = (unsigned)kRes[l];
            const unsigned R2 = R * R;
            const float scale = (float)(kRes[l] - 1);
            const u32x4* qt = quad + kOff[l];
            const float px = x * scale, py = y * scale, pz = z * scale;
            const float fx = floorf(px), fy = floorf(py), fz = floorf(pz);
            const float rx = px - fx, ry = py - fy, rz = pz - fz;
            const unsigned ix = (unsigned)fx, iy = (unsigned)fy,
                           iz = (unsigned)fz;
            const unsigned base = ix + iy * R + iz * R2;
            const u32x4 q0 = qt[base];
            const u32x4 q1 = qt[base + R2];
            const float wx0 = 1.0f - rx, wx1 = rx;
            const float wy0 = 1.0f - ry, wy1 = ry;
            const float wz0 = 1.0f - rz, wz1 = rz;
            const float ex00 = wx0 * lo2f(q0.x) + wx1 * lo2f(q0.y);
            const float ey00 = wx0 * hi2f(q0.x) + wx1 * hi2f(q0.y);
            const float ex10 = wx0 * lo2f(q0.z) + wx1 * lo2f(q0.w);
            const float ey10 = wx0 * hi2f(q0.z) + wx1 * hi2f(q0.w);
            const float ex01 = wx0 * lo2f(q1.x) + wx1 * lo2f(q1.y);
            const float ey01 = wx0 * hi2f(q1.x) + wx1 * hi2f(q1.y);
            const float ex11 = wx0 * lo2f(q1.z) + wx1 * lo2f(q1.w);
            const float ey11 = wx0 * hi2f(q1.z) + wx1 * hi2f(q1.w);
            const float sx = wz0 * (wy0 * ex00 + wy1 * ex10) +
                             wz1 * (wy0 * ex01 + wy1 * ex11);
            const float sy = wz0 * (wy0 * ey00 + wy1 * ey10) +
                             wz1 * (wy0 * ey01 + wy1 * ey11);
            s[t * 13 + l] = pkh2(sx, sy);
        }
        // dense level 4: pair gathers (8B entries)
        {
            constexpr unsigned R = 64, R2 = 4096;
            constexpr float scale = 63.0f;
            const float px = x * scale, py = y * scale, pz = z * scale;
            const float fx = floorf(px), fy = floorf(py), fz = floorf(pz);
            const float rx = px - fx, ry = py - fy, rz = pz - fz;
            const unsigned ix = (unsigned)fx, iy = (unsigned)fy,
                           iz = (unsigned)fz;
            const unsigned base = ix + iy * R + iz * R2;
            const u32x2 q00 = pair4[base];
            const u32x2 q10 = pair4[base + R];
            const u32x2 q01 = pair4[base + R2];
            const u32x2 q11 = pair4[base + R2 + R];
            const float wx0 = 1.0f - rx, wx1 = rx;
            const float wy0 = 1.0f - ry, wy1 = ry;
            const float wz0 = 1.0f - rz, wz1 = rz;
            const float w00 = wy0 * wz0, w10 = wy1 * wz0;
            const float w01 = wy0 * wz1, w11 = wy1 * wz1;
            float sx = 0.0f, sy = 0.0f;
            sx = fmaf(w00 * wx0, lo2f(q00.x), fmaf(w00 * wx1, lo2f(q00.y), sx));
            sy = fmaf(w00 * wx0, hi2f(q00.x), fmaf(w00 * wx1, hi2f(q00.y), sy));
            sx = fmaf(w10 * wx0, lo2f(q10.x), fmaf(w10 * wx1, lo2f(q10.y), sx));
            sy = fmaf(w10 * wx0, hi2f(q10.x), fmaf(w10 * wx1, hi2f(q10.y), sy));
            sx = fmaf(w01 * wx0, lo2f(q01.x), fmaf(w01 * wx1, lo2f(q01.y), sx));
            sy = fmaf(w01 * wx0, hi2f(q01.x), fmaf(w01 * wx1, hi2f(q01.y), sy));
            sx = fmaf(w11 * wx0, lo2f(q11.x), fmaf(w11 * wx1, lo2f(q11.y), sx));
            sy = fmaf(w11 * wx0, hi2f(q11.x), fmaf(w11 * wx1, hi2f(q11.y), sy));
            s[t * 13 + 4] = pkh2(sx, sy);
        }
        // hash levels 5..11: ROLLED loop (runtime consts -> low VGPR)
        for (int l = 5; l < NLEV; ++l) {
            const float scale = (float)(kRes[l] - 1);
            s[t * 13 + l] = encode_hash_rt(x, y, z, packed + kOff[l], scale);
        }
    }
    __syncthreads();

    // coalesced point-major write: 3072 u32 per block (48B per point)
    const long long base = (long long)blockIdx.x * (BLOCK * NLEV);
    const long long lim = (long long)N * NLEV;
#pragma unroll
    for (int k = 0; k < NLEV; ++k) {
        const int m = k * BLOCK + t;         // block-local u32 index
        const long long gi = base + m;
        if (gi < lim) {
            const int r = m / NLEV;          // row (magic-mul)
            const int l = m - r * NLEV;      // level
            __builtin_nontemporal_store(s[r * 13 + l], &pm_u32[gi]);
        }
    }
}

// ---- assemble: out[n] <- pm[rank[n]] (48B row), coalesced nt out ----
__global__ void __launch_bounds__(BLOCK)
assemble_kernel(const unsigned* __restrict__ pm_u32,
                const unsigned* __restrict__ rank,
                float* __restrict__ out, int N)
{
    __shared__ float s_out[BLOCK * 25];
    const int t = threadIdx.x;
    const int n = blockIdx.x * BLOCK + t;

    if (n < N) {
        const unsigned pos = rank[n];
        const u32x4* row = reinterpret_cast<const u32x4*>(pm_u32 +
                                                          (long long)pos * 12);
        const u32x4 qa = row[0];
        const u32x4 qb = row[1];
        const u32x4 qc = row[2];
        unsigned r[NLEV] = {qa.x, qa.y, qa.z, qa.w,
                            qb.x, qb.y, qb.z, qb.w,
                            qc.x, qc.y, qc.z, qc.w};
#pragma unroll
        for (int l = 0; l < NLEV; ++l) {
            s_out[t * 25 + 2 * l + 0] = lo2f(r[l]);
            s_out[t * 25 + 2 * l + 1] = hi2f(r[l]);
        }
    }
    __syncthreads();

    const long long base = (long long)blockIdx.x * (BLOCK * 24);
    const long long lim = (long long)N * 24;
#pragma unroll
    for (int k = 0; k < 24; ++k) {
        const int g = k * BLOCK + t;
        const long long gg = base + g;
        if (gg < lim) {
            const int nl = g / 24;   // magic-mul division
            const int j = g - nl * 24;
            __builtin_nontemporal_store(s_out[nl * 25 + j], &out[gg]);
        }
    }
}

// ---- fallback: fused single-kernel on f32 table (ws too small) ----
__global__ void __launch_bounds__(BLOCK, 4)
fused_kernel(const float* __restrict__ inp, const float2* __restrict__ table,
             float* __restrict__ out, int N)
{
    __shared__ float s_out[BLOCK * 25];
    const int t = threadIdx.x;
    const int n = blockIdx.x * BLOCK + t;

    if (n < N) {
        const float x = inp[n * 3 + 0];
        const float y = inp[n * 3 + 1];
        const float z = inp[n * 3 + 2];

#pragma unroll
        for (int l = 0; l < NLEV; ++l) {
            const int R = kRes[l];
            const bool HASH = (l >= 5);
            const float scale = (float)(R - 1);
            const float px = x * scale, py = y * scale, pz = z * scale;
            const float fx = floorf(px), fy = floorf(py), fz = floorf(pz);
            const float wx = px - fx, wy = py - fy, wz = pz - fz;
            const unsigned ix = (unsigned)fx, iy = (unsigned)fy,
                           iz = (unsigned)fz;
            unsigned x0, x1, y0, y1, z0, z1;
            if (HASH) {
                x0 = ix;      x1 = ix + 1u;
                y0 = iy * P1; y1 = y0 + P1;
                z0 = iz * P2; z1 = z0 + P2;
            } else {
                const unsigned Ru = (unsigned)R, R2 = Ru * Ru;
                x0 = ix;      x1 = ix + 1u;
                y0 = iy * Ru; y1 = y0 + Ru;
                z0 = iz * R2; z1 = z0 + R2;
            }
            unsigned idx[8];
            if (HASH) {
                idx[0] = (x0 ^ y0 ^ z0) & HMASK; idx[1] = (x1 ^ y0 ^ z0) & HMASK;
                idx[2] = (x0 ^ y1 ^ z0) & HMASK; idx[3] = (x1 ^ y1 ^ z0) & HMASK;
                idx[4] = (x0 ^ y0 ^ z1) & HMASK; idx[5] = (x1 ^ y0 ^ z1) & HMASK;
                idx[6] = (x0 ^ y1 ^ z1) & HMASK; idx[7] = (x1 ^ y1 ^ z1) & HMASK;
            } else {
                idx[0] = x0 + y0 + z0; idx[1] = x1 + y0 + z0;
                idx[2] = x0 + y1 + z0; idx[3] = x1 + y1 + z0;
                idx[4] = x0 + y0 + z1; idx[5] = x1 + y0 + z1;
                idx[6] = x0 + y1 + z1; idx[7] = x1 + y1 + z1;
            }
            const float w0x = 1.0f - wx, w0y = 1.0f - wy, w0z = 1.0f - wz;
            const float w00 = w0x * w0y, w10 = wx * w0y;
            const float w01 = w0x * wy,  w11 = wx * wy;
            const float wt[8] = {w00 * w0z, w10 * w0z, w01 * w0z, w11 * w0z,
                                 w00 * wz,  w10 * wz,  w01 * wz,  w11 * wz};
            float sx = 0.0f, sy = 0.0f;
#pragma unroll
            for (int c = 0; c < 8; ++c) {
                float2 e = table[kOff[l] + idx[c]];
                sx = fmaf(wt[c], e.x, sx);
                sy = fmaf(wt[c], e.y, sy);
            }
            s_out[t * 25 + 2 * l + 0] = sx;
            s_out[t * 25 + 2 * l + 1] = sy;
        }
    }
    __syncthreads();
    const long long base = (long long)blockIdx.x * (BLOCK * 24);
    const long long lim = (long long)N * 24;
#pragma unroll
    for (int k = 0; k < 24; ++k) {
        const int g = k * BLOCK + t;
        const long long gg = base + g;
        if (gg < lim) {
            const int nl = g / 24;
            const int j = g - nl * 24;
            out[gg] = s_out[nl * 25 + j];
        }
    }
}

extern "C" void kernel_launch(void* const* d_in, const int* in_sizes, int n_in,
                              void* d_out, int out_size, void* d_ws, size_t ws_size,
                              hipStream_t stream) {
    const float* inputs = (const float*)d_in[0];
    const float* embeddings = (const float*)d_in[1];
    // d_in[2]/d_in[3] (offsets/resolutions) are compile-time constants here.
    float* out = (float*)d_out;

    const int N = in_sizes[0] / 3;            // 2,000,000
    const int total = in_sizes[1] / 2;        // 4,078,528 table entries

    const size_t quad_bytes = (size_t)DENSE_A_END * 16;           // 2.34 MB
    const size_t pair4_bytes = (size_t)L4_SIZE * 8;               // 2.0 MB
    const size_t packed_bytes = (size_t)total * sizeof(unsigned); // 16.3 MB
    const size_t pm_bytes = (size_t)N * 48;                       // 96 MB
    const size_t perm_bytes = (size_t)N * 4;                      // 8 MB
    const size_t rank_bytes = (size_t)N * 4;                      // 8 MB
    const size_t hist_bytes = (size_t)NBUCK * 4;                  // 1 MB
    const size_t seg_bytes = 256 * 4;

    const int ngrid = (N + BLOCK - 1) / BLOCK;
    const int pgrid = (total + BLOCK - 1) / BLOCK;

    const size_t full_need = quad_bytes + pair4_bytes + packed_bytes +
                             pm_bytes + perm_bytes + rank_bytes +
                             hist_bytes + seg_bytes;   // ~133.8 MB (proven)

    if (ws_size >= full_need) {
        char* w = (char*)d_ws;
        u32x4* quad = (u32x4*)w;                  w += quad_bytes;
        u32x2* pair4 = (u32x2*)w;                 w += pair4_bytes;
        unsigned* packed = (unsigned*)w;          w += packed_bytes;
        unsigned* pm = (unsigned*)w;              w += pm_bytes;
        unsigned* perm = (unsigned*)w;            w += perm_bytes;
        unsigned* rank = (unsigned*)w;            w += rank_bytes;
        unsigned* hist = (unsigned*)w;            w += hist_bytes;
        unsigned* segsum = (unsigned*)w;

        pack_all_kernel<<<pgrid, BLOCK, 0, stream>>>(
            (const float2*)embeddings, packed, quad, pair4, total);

        hipMemsetAsync(hist, 0, hist_bytes, stream);
        hist_kernel<<<ngrid, BLOCK, 0, stream>>>(inputs, hist, N);
        scanA_kernel<<<256, BLOCK, 0, stream>>>(hist, segsum);
        scanB_kernel<<<1, BLOCK, 0, stream>>>(segsum);
        scanC_kernel<<<256, BLOCK, 0, stream>>>(hist, segsum);
        scatter_kernel<<<ngrid, BLOCK, 0, stream>>>(inputs, hist, perm, rank, N);

        fused_pm_kernel<<<ngrid, BLOCK, 0, stream>>>(
            inputs, perm, quad, pair4, packed, pm, N);

        assemble_kernel<<<ngrid, BLOCK, 0, stream>>>(pm, rank, out, N);
    } else {
        fused_kernel<<<ngrid, BLOCK, 0, stream>>>(
            inputs, (const float2*)embeddings, out, N);
    }
}

// Round 17
// 487.204 us; speedup vs baseline: 1.4503x; 1.2753x over previous
//
#include <hip/hip_runtime.h>
#include <hip/hip_fp16.h>

// Instant-NGP grid encoder, MI355X (gfx950).
// N=2,000,000 points [N,3] f32 in [0,1); 12 levels, F=2; out [N,24] f32.
// res: 16,23,32,46,64,92,128,184,256,368,512,736; hash iff r^3>2^19
// (levels 5..11, each exactly 2^19 entries -> & 0x7FFFF). Dense: no modulo.
//
// Round-17: REVERT to round-13 (best measured: 487us total, mega 453us).
//   r14-r16 explored Morton-sorted gathers: sort cuts the gather phase
//   455->262us (transaction model confirmed) but sort pipeline (~90us) +
//   sorted->original assembly (~120-180us vs 46us) + launch gaps cancel
//   the win (all variants 600-710us; perfect-plumbing estimate ~490-530).
//   r13's level-phased mega keeps each level's 2MB table XCD-L2-resident
//   (FETCH 190MB vs 924MB when level-mixed) and sits at the TCP
//   distinct-line transaction-rate limit for spatially-random gathers.

namespace {
constexpr int NLEV = 12;
constexpr int BLOCK = 256;
constexpr int DENSE_A_END = 146368;   // levels 0..3
constexpr int L4_SIZE = 262144;       // level 4 (64^3)
constexpr unsigned P1 = 2654435761u;
constexpr unsigned P2 = 805459861u;
constexpr unsigned HMASK = (1u << 19) - 1u;

__device__ __constant__ constexpr int kRes[NLEV] = {
    16, 23, 32, 46, 64, 92, 128, 184, 256, 368, 512, 736};
__device__ __constant__ constexpr int kOff[NLEV] = {
    0, 4096, 16264, 49032, 146368, 408512,
    932800, 1457088, 1981376, 2505664, 3029952, 3554240};

typedef float    f32x2 __attribute__((ext_vector_type(2)));
typedef unsigned u32x2 __attribute__((ext_vector_type(2)));
typedef unsigned u32x4 __attribute__((ext_vector_type(4)));
typedef int      i32x4 __attribute__((ext_vector_type(4)));

__device__ __forceinline__ unsigned pkh2(float a, float b) {
    __half2 h = __floats2half2_rn(a, b);
    return *reinterpret_cast<unsigned*>(&h);
}
__device__ __forceinline__ float lo2f(unsigned u) {
    __half2 h = *reinterpret_cast<__half2*>(&u);
    return __low2float(h);
}
__device__ __forceinline__ float hi2f(unsigned u) {
    __half2 h = *reinterpret_cast<__half2*>(&u);
    return __high2float(h);
}
}  // namespace

// ---- raw buffer loads with cache-policy (CK-style intrinsic decls) ----
extern "C" __device__ unsigned
llvm_buf_ld_b32(i32x4, unsigned, unsigned, unsigned)
    __asm("llvm.amdgcn.raw.buffer.load.i32");
extern "C" __device__ u32x2
llvm_buf_ld_b64(i32x4, unsigned, unsigned, unsigned)
    __asm("llvm.amdgcn.raw.buffer.load.v2i32");
extern "C" __device__ u32x4
llvm_buf_ld_b128(i32x4, unsigned, unsigned, unsigned)
    __asm("llvm.amdgcn.raw.buffer.load.v4i32");

__device__ __forceinline__ i32x4 make_rsrc(const void* p) {
    unsigned long long a = (unsigned long long)p;
    i32x4 r;
    r.x = (int)(unsigned)(a & 0xFFFFFFFFull);
    r.y = (int)(unsigned)(a >> 32);   // stride=0
    r.z = -1;                          // num_records: bounds check off
    r.w = 0x00020000;                  // raw dword buffer
    return r;
}
// aux=1 -> SC0 (device scope) on gfx94x/95x; measured neutral vs plain
// loads (r13 == r10 within noise) and keeps VGPR low via 32b voffsets.
__device__ __forceinline__ unsigned g32(i32x4 r, unsigned byteoff) {
    return llvm_buf_ld_b32(r, byteoff, 0, 1);
}
__device__ __forceinline__ u32x2 g64(i32x4 r, unsigned byteoff) {
    return llvm_buf_ld_b64(r, byteoff, 0, 1);
}
__device__ __forceinline__ u32x4 g128(i32x4 r, unsigned byteoff) {
    return llvm_buf_ld_b128(r, byteoff, 0, 1);
}

// ---- fused pre-pass: packed (all), quad (levels 0-3), pair4 (level 4) ----
__global__ void __launch_bounds__(BLOCK)
pack_all_kernel(const float2* __restrict__ emb,
                unsigned* __restrict__ packed,
                u32x4* __restrict__ quad,
                u32x2* __restrict__ pair4, int total)
{
    int i = blockIdx.x * BLOCK + threadIdx.x;
    if (i >= total) return;
    float2 v = emb[i];
    packed[i] = pkh2(v.x, v.y);
    if (i < DENSE_A_END) {
        int R = (i < 4096) ? 16 : (i < 16264) ? 23 : (i < 49032) ? 32 : 46;
        float2 e1 = emb[i + 1];
        float2 e2 = emb[i + R];
        float2 e3 = emb[i + R + 1];
        u32x4 q;
        q.x = pkh2(v.x, v.y);   q.y = pkh2(e1.x, e1.y);
        q.z = pkh2(e2.x, e2.y); q.w = pkh2(e3.x, e3.y);
        quad[i] = q;
    }
    if (i < L4_SIZE) {
        int g = DENSE_A_END + i;
        float2 a = emb[g];
        float2 b = emb[g + 1];
        u32x2 o; o.x = pkh2(a.x, a.y); o.y = pkh2(b.x, b.y);
        pair4[i] = o;
    }
}

// ---- hash level encode; lvlbase = byte offset of level table ----
__device__ __forceinline__ unsigned
encode_hash_rt(float x, float y, float z, i32x4 rsrc, unsigned lvlbase,
               float scale)
{
    const float px = x * scale, py = y * scale, pz = z * scale;
    const float fx = floorf(px), fy = floorf(py), fz = floorf(pz);
    const float rx = px - fx, ry = py - fy, rz = pz - fz;
    const unsigned ix = (unsigned)fx, iy = (unsigned)fy, iz = (unsigned)fz;
    const unsigned yA = iy * P1, yB = yA + P1;
    const unsigned zA = iz * P2, zB = zA + P2;
    const unsigned h00 = (ix ^ yA ^ zA) & HMASK;
    const unsigned h10 = (ix ^ yB ^ zA) & HMASK;
    const unsigned h01 = (ix ^ yA ^ zB) & HMASK;
    const unsigned h11 = (ix ^ yB ^ zB) & HMASK;

    // aligned x-pair words: {h, h^1} live in one 8B-aligned u32x2
    const u32x2 q00 = g64(rsrc, lvlbase + (h00 & ~1u) * 4u);
    const u32x2 q10 = g64(rsrc, lvlbase + (h10 & ~1u) * 4u);
    const u32x2 q01 = g64(rsrc, lvlbase + (h01 & ~1u) * 4u);
    const u32x2 q11 = g64(rsrc, lvlbase + (h11 & ~1u) * 4u);

    unsigned e00 = (h00 & 1) ? q00.y : q00.x;
    unsigned e10 = (h10 & 1) ? q10.y : q10.x;
    unsigned e01 = (h01 & 1) ? q01.y : q01.x;
    unsigned e11 = (h11 & 1) ? q11.y : q11.x;
    unsigned f00 = (h00 & 1) ? q00.x : q00.y;
    unsigned f10 = (h10 & 1) ? q10.x : q10.y;
    unsigned f01 = (h01 & 1) ? q01.x : q01.y;
    unsigned f11 = (h11 & 1) ? q11.x : q11.y;

    if (ix & 1u) {  // odd ix: sibling word is ix-1; need real ix+1 entries
        const unsigned xo = ix + 1u;
        f00 = g32(rsrc, lvlbase + ((xo ^ yA ^ zA) & HMASK) * 4u);
        f10 = g32(rsrc, lvlbase + ((xo ^ yB ^ zA) & HMASK) * 4u);
        f01 = g32(rsrc, lvlbase + ((xo ^ yA ^ zB) & HMASK) * 4u);
        f11 = g32(rsrc, lvlbase + ((xo ^ yB ^ zB) & HMASK) * 4u);
    }

    const float wx0 = 1.0f - rx, wx1 = rx;
    const float wy0 = 1.0f - ry, wy1 = ry;
    const float wz0 = 1.0f - rz, wz1 = rz;
    const float w00 = wy0 * wz0, w10 = wy1 * wz0;
    const float w01 = wy0 * wz1, w11 = wy1 * wz1;
    float sx = 0.0f, sy = 0.0f;
    sx = fmaf(w00 * wx0, lo2f(e00), fmaf(w00 * wx1, lo2f(f00), sx));
    sy = fmaf(w00 * wx0, hi2f(e00), fmaf(w00 * wx1, hi2f(f00), sy));
    sx = fmaf(w10 * wx0, lo2f(e10), fmaf(w10 * wx1, lo2f(f10), sx));
    sy = fmaf(w10 * wx0, hi2f(e10), fmaf(w10 * wx1, hi2f(f10), sy));
    sx = fmaf(w01 * wx0, lo2f(e01), fmaf(w01 * wx1, lo2f(f01), sx));
    sy = fmaf(w01 * wx0, hi2f(e01), fmaf(w01 * wx1, hi2f(f01), sy));
    sx = fmaf(w11 * wx0, lo2f(e11), fmaf(w11 * wx1, lo2f(f11), sx));
    sy = fmaf(w11 * wx0, hi2f(e11), fmaf(w11 * wx1, hi2f(f11), sy));
    return pkh2(sx, sy);
}

// ---- MEGA: blocks [0,CB)=dense_a, [CB,2CB)=dense_b, [2CB,9CB)=hash5..11 ----
__global__ void __launch_bounds__(BLOCK)
mega_kernel(const float* __restrict__ inp,
            const u32x4* __restrict__ quad,
            const u32x2* __restrict__ pair4,
            const unsigned* __restrict__ packed,
            unsigned* __restrict__ stage, int N, int CB)
{
    const int b = blockIdx.x;
    const int t = b / CB;            // task id (block-uniform)
    const int chunk = b - t * CB;
    const int g = chunk * BLOCK + threadIdx.x;   // point-pair index
    const int p0 = 2 * g;
    if (p0 >= N) return;
    const bool two = (p0 + 1 < N);

    const f32x2* ip2 = reinterpret_cast<const f32x2*>(inp);
    f32x2 v0 = ip2[3 * g + 0];
    f32x2 v1, v2;
    if (two) { v1 = ip2[3 * g + 1]; v2 = ip2[3 * g + 2]; }
    else { v1.x = inp[3 * p0 + 2]; v1.y = 0.f; v2.x = 0.f; v2.y = 0.f; }
    const float X[2] = {v0.x, v1.y};
    const float Y[2] = {v0.y, v2.x};
    const float Z[2] = {v1.x, v2.y};

    if (t == 0) {
        // dense levels 0..3, sc0 quad gathers (16B entries)
        const i32x4 qr = make_rsrc(quad);
#pragma unroll
        for (int l = 0; l < 4; ++l) {
            const unsigned R = (unsigned)kRes[l];
            const unsigned R2 = R * R;
            const float scale = (float)(kRes[l] - 1);
            const unsigned lvlbase = (unsigned)kOff[l] * 16u;
            u32x2 res;
#pragma unroll
            for (int k = 0; k < 2; ++k) {
                const float px = X[k] * scale, py = Y[k] * scale,
                            pz = Z[k] * scale;
                const float fx = floorf(px), fy = floorf(py), fz = floorf(pz);
                const float rx = px - fx, ry = py - fy, rz = pz - fz;
                const unsigned ix = (unsigned)fx, iy = (unsigned)fy,
                               iz = (unsigned)fz;
                const unsigned base = ix + iy * R + iz * R2;
                const u32x4 q0 = g128(qr, lvlbase + base * 16u);
                const u32x4 q1 = g128(qr, lvlbase + (base + R2) * 16u);
                const float wx0 = 1.0f - rx, wx1 = rx;
                const float wy0 = 1.0f - ry, wy1 = ry;
                const float wz0 = 1.0f - rz, wz1 = rz;
                const float ex00 = wx0 * lo2f(q0.x) + wx1 * lo2f(q0.y);
                const float ey00 = wx0 * hi2f(q0.x) + wx1 * hi2f(q0.y);
                const float ex10 = wx0 * lo2f(q0.z) + wx1 * lo2f(q0.w);
                const float ey10 = wx0 * hi2f(q0.z) + wx1 * hi2f(q0.w);
                const float ex01 = wx0 * lo2f(q1.x) + wx1 * lo2f(q1.y);
                const float ey01 = wx0 * hi2f(q1.x) + wx1 * hi2f(q1.y);
                const float ex11 = wx0 * lo2f(q1.z) + wx1 * lo2f(q1.w);
                const float ey11 = wx0 * hi2f(q1.z) + wx1 * hi2f(q1.w);
                const float sx = wz0 * (wy0 * ex00 + wy1 * ex10) +
                                 wz1 * (wy0 * ex01 + wy1 * ex11);
                const float sy = wz0 * (wy0 * ey00 + wy1 * ey10) +
                                 wz1 * (wy0 * ey01 + wy1 * ey11);
                res[k] = pkh2(sx, sy);
            }
            if (two) {
                __builtin_nontemporal_store(
                    res,
                    reinterpret_cast<u32x2*>(&stage[(long long)l * N + p0]));
            } else {
                __builtin_nontemporal_store(res.x,
                                            &stage[(long long)l * N + p0]);
            }
        }
    } else if (t == 1) {
        // dense level 4 (64^3), sc0 pair gathers (8B entries)
        const i32x4 pr = make_rsrc(pair4);
        constexpr unsigned R = 64, R2 = 4096;
        constexpr float scale = 63.0f;
        u32x2 res;
#pragma unroll
        for (int k = 0; k < 2; ++k) {
            const float px = X[k] * scale, py = Y[k] * scale, pz = Z[k] * scale;
            const float fx = floorf(px), fy = floorf(py), fz = floorf(pz);
            const float rx = px - fx, ry = py - fy, rz = pz - fz;
            const unsigned ix = (unsigned)fx, iy = (unsigned)fy,
                           iz = (unsigned)fz;
            const unsigned base = ix + iy * R + iz * R2;
            const u32x2 q00 = g64(pr, base * 8u);
            const u32x2 q10 = g64(pr, (base + R) * 8u);
            const u32x2 q01 = g64(pr, (base + R2) * 8u);
            const u32x2 q11 = g64(pr, (base + R2 + R) * 8u);
            const float wx0 = 1.0f - rx, wx1 = rx;
            const float wy0 = 1.0f - ry, wy1 = ry;
            const float wz0 = 1.0f - rz, wz1 = rz;
            const float w00 = wy0 * wz0, w10 = wy1 * wz0;
            const float w01 = wy0 * wz1, w11 = wy1 * wz1;
            float sx = 0.0f, sy = 0.0f;
            sx = fmaf(w00 * wx0, lo2f(q00.x), fmaf(w00 * wx1, lo2f(q00.y), sx));
            sy = fmaf(w00 * wx0, hi2f(q00.x), fmaf(w00 * wx1, hi2f(q00.y), sy));
            sx = fmaf(w10 * wx0, lo2f(q10.x), fmaf(w10 * wx1, lo2f(q10.y), sx));
            sy = fmaf(w10 * wx0, hi2f(q10.x), fmaf(w10 * wx1, hi2f(q10.y), sy));
            sx = fmaf(w01 * wx0, lo2f(q01.x), fmaf(w01 * wx1, lo2f(q01.y), sx));
            sy = fmaf(w01 * wx0, hi2f(q01.x), fmaf(w01 * wx1, hi2f(q01.y), sy));
            sx = fmaf(w11 * wx0, lo2f(q11.x), fmaf(w11 * wx1, lo2f(q11.y), sx));
            sy = fmaf(w11 * wx0, hi2f(q11.x), fmaf(w11 * wx1, hi2f(q11.y), sy));
            res[k] = pkh2(sx, sy);
        }
        unsigned* s4 = stage + 4LL * N;
        if (two) {
            __builtin_nontemporal_store(res, reinterpret_cast<u32x2*>(&s4[p0]));
        } else {
            __builtin_nontemporal_store(res.x, &s4[p0]);
        }
    } else {
        // hash level L = t + 3 (t=2..8 -> L=5..11), sc0 gathers
        const int L = t + 3;
        const float scale = (float)(kRes[L] - 1);
        const i32x4 hr = make_rsrc(packed);
        const unsigned lvlbase = (unsigned)kOff[L] * 4u;
        u32x2 res;
        res.x = encode_hash_rt(X[0], Y[0], Z[0], hr, lvlbase, scale);
        res.y = two ? encode_hash_rt(X[1], Y[1], Z[1], hr, lvlbase, scale) : 0u;
        unsigned* sl = stage + (long long)L * N;
        if (two) {
            __builtin_nontemporal_store(res, reinterpret_cast<u32x2*>(&sl[p0]));
        } else {
            __builtin_nontemporal_store(res.x, &sl[p0]);
        }
    }
}

// ---- final: [12][N] fp16x2 -> [N][24] f32, LDS transpose ----
__global__ void __launch_bounds__(BLOCK)
assemble_kernel(const unsigned* __restrict__ lvl, float* __restrict__ out,
                int N)
{
    __shared__ float s_out[BLOCK * 25];
    const int t = threadIdx.x;
    const int n = blockIdx.x * BLOCK + t;

    if (n < N) {
#pragma unroll
        for (int l = 0; l < NLEV; ++l) {
            unsigned u = __builtin_nontemporal_load(&lvl[(long long)l * N + n]);
            s_out[t * 25 + 2 * l + 0] = lo2f(u);
            s_out[t * 25 + 2 * l + 1] = hi2f(u);
        }
    }
    __syncthreads();

    const long long base = (long long)blockIdx.x * (BLOCK * 24);
    const long long lim = (long long)N * 24;
#pragma unroll
    for (int k = 0; k < 24; ++k) {
        const int g = k * BLOCK + t;
        const long long gg = base + g;
        if (gg < lim) {
            const int nl = g / 24;   // magic-mul division
            const int j = g - nl * 24;
            __builtin_nontemporal_store(s_out[nl * 25 + j], &out[gg]);
        }
    }
}

// ---- fallback: fused single-kernel on f32 table (ws too small) ----
__global__ void __launch_bounds__(BLOCK, 4)
fused_kernel(const float* __restrict__ inp, const float2* __restrict__ table,
             float* __restrict__ out, int N)
{
    __shared__ float s_out[BLOCK * 25];
    const int t = threadIdx.x;
    const int n = blockIdx.x * BLOCK + t;

    if (n < N) {
        const float x = inp[n * 3 + 0];
        const float y = inp[n * 3 + 1];
        const float z = inp[n * 3 + 2];

#pragma unroll
        for (int l = 0; l < NLEV; ++l) {
            const int R = kRes[l];
            const bool HASH = (l >= 5);
            const float scale = (float)(R - 1);
            const float px = x * scale, py = y * scale, pz = z * scale;
            const float fx = floorf(px), fy = floorf(py), fz = floorf(pz);
            const float wx = px - fx, wy = py - fy, wz = pz - fz;
            const unsigned ix = (unsigned)fx, iy = (unsigned)fy,
                           iz = (unsigned)fz;
            unsigned x0, x1, y0, y1, z0, z1;
            if (HASH) {
                x0 = ix;      x1 = ix + 1u;
                y0 = iy * P1; y1 = y0 + P1;
                z0 = iz * P2; z1 = z0 + P2;
            } else {
                const unsigned Ru = (unsigned)R, R2 = Ru * Ru;
                x0 = ix;      x1 = ix + 1u;
                y0 = iy * Ru; y1 = y0 + Ru;
                z0 = iz * R2; z1 = z0 + R2;
            }
            unsigned idx[8];
            if (HASH) {
                idx[0] = (x0 ^ y0 ^ z0) & HMASK; idx[1] = (x1 ^ y0 ^ z0) & HMASK;
                idx[2] = (x0 ^ y1 ^ z0) & HMASK; idx[3] = (x1 ^ y1 ^ z0) & HMASK;
                idx[4] = (x0 ^ y0 ^ z1) & HMASK; idx[5] = (x1 ^ y0 ^ z1) & HMASK;
                idx[6] = (x0 ^ y1 ^ z1) & HMASK; idx[7] = (x1 ^ y1 ^ z1) & HMASK;
            } else {
                idx[0] = x0 + y0 + z0; idx[1] = x1 + y0 + z0;
                idx[2] = x0 + y1 + z0; idx[3] = x1 + y1 + z0;
                idx[4] = x0 + y0 + z1; idx[5] = x1 + y0 + z1;
                idx[6] = x0 + y1 + z1; idx[7] = x1 + y1 + z1;
            }
            const float w0x = 1.0f - wx, w0y = 1.0f - wy, w0z = 1.0f - wz;
            const float w00 = w0x * w0y, w10 = wx * w0y;
            const float w01 = w0x * wy,  w11 = wx * wy;
            const float wt[8] = {w00 * w0z, w10 * w0z, w01 * w0z, w11 * w0z,
                                 w00 * wz,  w10 * wz,  w01 * wz,  w11 * wz};
            float sx = 0.0f, sy = 0.0f;
#pragma unroll
            for (int c = 0; c < 8; ++c) {
                float2 e = table[kOff[l] + idx[c]];
                sx = fmaf(wt[c], e.x, sx);
                sy = fmaf(wt[c], e.y, sy);
            }
            s_out[t * 25 + 2 * l + 0] = sx;
            s_out[t * 25 + 2 * l + 1] = sy;
        }
    }
    __syncthreads();
    const long long base = (long long)blockIdx.x * (BLOCK * 24);
    const long long lim = (long long)N * 24;
#pragma unroll
    for (int k = 0; k < 24; ++k) {
        const int g = k * BLOCK + t;
        const long long gg = base + g;
        if (gg < lim) {
            const int nl = g / 24;
            const int j = g - nl * 24;
            out[gg] = s_out[nl * 25 + j];
        }
    }
}

extern "C" void kernel_launch(void* const* d_in, const int* in_sizes, int n_in,
                              void* d_out, int out_size, void* d_ws, size_t ws_size,
                              hipStream_t stream) {
    const float* inputs = (const float*)d_in[0];
    const float* embeddings = (const float*)d_in[1];
    // d_in[2]/d_in[3] (offsets/resolutions) are compile-time constants here.
    float* out = (float*)d_out;

    const int N = in_sizes[0] / 3;            // 2,000,000
    const int total = in_sizes[1] / 2;        // 4,078,528 table entries

    const size_t quad_bytes = (size_t)DENSE_A_END * 16;           // 2.34 MB
    const size_t pair4_bytes = (size_t)L4_SIZE * 8;               // 2.0 MB
    const size_t packed_bytes = (size_t)total * sizeof(unsigned); // 16.3 MB
    const size_t stage_bytes = (size_t)NLEV * N * sizeof(unsigned); // 96 MB

    const int ngrid = (N + BLOCK - 1) / BLOCK;

    if (ws_size >= quad_bytes + pair4_bytes + packed_bytes + stage_bytes) {
        char* w = (char*)d_ws;
        u32x4* quad = (u32x4*)w;                  w += quad_bytes;
        u32x2* pair4 = (u32x2*)w;                 w += pair4_bytes;
        unsigned* packed = (unsigned*)w;          w += packed_bytes;
        unsigned* stage = (unsigned*)w;

        pack_all_kernel<<<(total + BLOCK - 1) / BLOCK, BLOCK, 0, stream>>>(
            (const float2*)embeddings, packed, quad, pair4, total);

        const int pairs = (N + 1) / 2;
        const int CB = (pairs + BLOCK - 1) / BLOCK;   // chunks per task
        mega_kernel<<<9 * CB, BLOCK, 0, stream>>>(
            inputs, quad, pair4, packed, stage, N, CB);

        assemble_kernel<<<ngrid, BLOCK, 0, stream>>>(stage, out, N);
    } else {
        fused_kernel<<<ngrid, BLOCK, 0, stream>>>(
            inputs, (const float2*)embeddings, out, N);
    }
}